// Round 1
// baseline (5230.901 us; speedup 1.0000x reference)
//
#include <hip/hip_runtime.h>
#include <cmath>

#define EPSF 1e-5f
constexpr int Qn   = 16384;
constexpr int Kn   = 16;
constexpr int DATT = 138;   // attention feature dim
constexpr int DSTR = 140;   // padded LDS stride (mult of 4, 2-way bank at worst)
constexpr int DLB  = 128;
constexpr int DSC  = 64;
constexpr int DMID = 74;
constexpr int CH   = 46;    // weight-chunk rows (3*46 = 138)
constexpr int Nd   = 4096;

// ---------------- Stage 1: rppe_lb/sc + concat + att_pool1 -> f_tilde ----------------
__global__ __launch_bounds__(256) void stage1(
    const float* __restrict__ feat_lb, const float* __restrict__ feat_sc,
    const int* __restrict__ nm_lb, const int* __restrict__ nm_sc,
    const float* __restrict__ c_lb, const float* __restrict__ c_sc,
    const float* __restrict__ c_q,
    const float* __restrict__ W_lb, const float* __restrict__ g_lb,
    const float* __restrict__ b_lb, const float* __restrict__ m_lb, const float* __restrict__ v_lb,
    const float* __restrict__ W_sc, const float* __restrict__ g_sc,
    const float* __restrict__ b_sc, const float* __restrict__ m_sc, const float* __restrict__ v_sc,
    const float* __restrict__ W_fc1, const float* __restrict__ W_mlp1,
    const float* __restrict__ g1, const float* __restrict__ b1,
    const float* __restrict__ m1, const float* __restrict__ v1,
    float* __restrict__ f_tilde)
{
    __shared__ __align__(16) float fhat[32][DSTR];
    __shared__ float att[32][DATT];
    __shared__ __align__(16) float Wc[CH * DSTR];
    __shared__ float px[32][10];
    __shared__ __align__(16) float agg_s[DSTR];

    const int bq  = blockIdx.x;      // b*Q + q
    const int b   = bq >> 14;
    const int tid = threadIdx.x;

    // ---- fill features into fhat (cols 10.. for lb rows, 74.. for sc rows) ----
    const float* flb = feat_lb + (size_t)bq * (Kn * DLB);
    for (int i = tid; i < Kn * DLB; i += 256)
        fhat[i >> 7][10 + (i & 127)] = flb[i];
    const float* fsc = feat_sc + (size_t)bq * (Kn * DSC);
    for (int i = tid; i < Kn * DSC; i += 256)
        fhat[16 + (i >> 6)][DMID + (i & 63)] = fsc[i];
    if (tid < 64) fhat[tid >> 1][DATT + (tid & 1)] = 0.f;   // zero pad cols 138,139

    // ---- phase A: rel-pos 10-vectors ----
    if (tid < 32) {
        const bool lb = tid < 16;
        const int  r  = tid & 15;
        const int  idx = lb ? nm_lb[bq * Kn + r] : nm_sc[bq * Kn + r];
        const float* nb = lb ? (c_lb + ((size_t)b * Nd + idx) * 3)
                             : (c_sc + ((size_t)b * Qn + idx) * 3);
        const float qx = c_q[bq * 3 + 0], qy = c_q[bq * 3 + 1], qz = c_q[bq * 3 + 2];
        const float nx = nb[0], ny = nb[1], nz = nb[2];
        const float rx = qx - nx, ry = qy - ny, rz = qz - nz;
        px[tid][0] = sqrtf(rx * rx + ry * ry + rz * rz);
        px[tid][1] = rx; px[tid][2] = ry; px[tid][3] = rz;
        px[tid][4] = qx; px[tid][5] = qy; px[tid][6] = qz;
        px[tid][7] = nx; px[tid][8] = ny; px[tid][9] = nz;
    }
    __syncthreads();

    // ---- phase B: small convs + BN + relu ----
    if (tid < 160) {
        const int r = tid / 10, o = tid - r * 10;
        float y = 0.f;
        #pragma unroll
        for (int c = 0; c < 10; ++c) y += px[r][c] * W_lb[o * 10 + c];
        y = (y - m_lb[o]) * (g_lb[o] * rsqrtf(v_lb[o] + EPSF)) + b_lb[o];
        fhat[r][o] = fmaxf(y, 0.f);
    }
    for (int e = tid; e < 16 * DMID; e += 256) {
        const int r = e / DMID, o = e - r * DMID;
        float y = 0.f;
        #pragma unroll
        for (int c = 0; c < 10; ++c) y += px[16 + r][c] * W_sc[o * 10 + c];
        y = (y - m_sc[o]) * (g_sc[o] * rsqrtf(v_sc[o] + EPSF)) + b_sc[o];
        fhat[16 + r][o] = fmaxf(y, 0.f);
    }

    // ---- phase C: att = fhat @ W_fc1^T, output cols chunked (3 x 46 rows of W) ----
    const int tr = tid >> 4, tc = tid & 15;
    const int r0 = tr * 2, r1 = r0 + 1;
    for (int chunk = 0; chunk < 3; ++chunk) {
        __syncthreads();
        const float* Wsrc = W_fc1 + chunk * CH * DATT;
        for (int i = tid; i < CH * DSTR; i += 256) {
            const int o = i / DSTR, c = i - o * DSTR;
            Wc[i] = (c < DATT) ? Wsrc[o * DATT + c] : 0.f;
        }
        __syncthreads();
        float acc0[3] = {0.f, 0.f, 0.f}, acc1[3] = {0.f, 0.f, 0.f};
        for (int c = 0; c < DSTR; c += 4) {
            const float4 a0 = *(const float4*)&fhat[r0][c];
            const float4 a1 = *(const float4*)&fhat[r1][c];
            #pragma unroll
            for (int j = 0; j < 3; ++j) {
                const int ol = tc + 16 * j;
                if (ol < CH) {
                    const float4 w = *(const float4*)&Wc[ol * DSTR + c];
                    acc0[j] += a0.x * w.x + a0.y * w.y + a0.z * w.z + a0.w * w.w;
                    acc1[j] += a1.x * w.x + a1.y * w.y + a1.z * w.z + a1.w * w.w;
                }
            }
        }
        #pragma unroll
        for (int j = 0; j < 3; ++j) {
            const int ol = tc + 16 * j;
            if (ol < CH) {
                const int o = chunk * CH + ol;
                att[r0][o] = acc0[j];
                att[r1][o] = acc1[j];
            }
        }
    }
    __syncthreads();

    // ---- softmax over 32 neighbors per channel + weighted aggregation ----
    if (tid < DSTR) {
        if (tid < DATT) {
            float mx = -1e30f;
            for (int r = 0; r < 32; ++r) mx = fmaxf(mx, att[r][tid]);
            float s = 0.f, a = 0.f;
            for (int r = 0; r < 32; ++r) {
                const float e = expf(att[r][tid] - mx);
                s += e;
                a += fhat[r][tid] * e;
            }
            agg_s[tid] = a / s;
        } else {
            agg_s[tid] = 0.f;
        }
    }

    // ---- MLP 138->128 + BN + relu, weight chunks staged in LDS ----
    for (int chunk = 0; chunk < 3; ++chunk) {
        __syncthreads();
        const int o0 = chunk * CH;
        const int nrows = (o0 + CH <= DLB) ? CH : (DLB - o0);   // 46,46,36
        const float* Wsrc = W_mlp1 + o0 * DATT;
        for (int i = tid; i < nrows * DSTR; i += 256) {
            const int o = i / DSTR, c = i - o * DSTR;
            Wc[i] = (c < DATT) ? Wsrc[o * DATT + c] : 0.f;
        }
        __syncthreads();
        if (tid < nrows) {
            const int o = o0 + tid;
            float y = 0.f;
            for (int c = 0; c < DSTR; c += 4) {
                const float4 w = *(const float4*)&Wc[tid * DSTR + c];
                const float4 a = *(const float4*)&agg_s[c];
                y += a.x * w.x + a.y * w.y + a.z * w.z + a.w * w.w;
            }
            y = (y - m1[o]) * (g1[o] * rsqrtf(v1[o] + EPSF)) + b1[o];
            f_tilde[(size_t)bq * DLB + o] = fmaxf(y, 0.f);
        }
    }
}

// ---------------- Stage 2: rppe_cl + gather f_tilde + att_pool2 -> out ----------------
__global__ __launch_bounds__(256) void stage2(
    const int* __restrict__ nm_cl, const float* __restrict__ c_q,
    const float* __restrict__ W_cl, const float* __restrict__ g_cl,
    const float* __restrict__ b_cl, const float* __restrict__ m_cl, const float* __restrict__ v_cl,
    const float* __restrict__ W_fc2, const float* __restrict__ W_mlp2,
    const float* __restrict__ g2, const float* __restrict__ b2,
    const float* __restrict__ m2, const float* __restrict__ v2,
    const float* __restrict__ f_tilde, float* __restrict__ out)
{
    __shared__ __align__(16) float fhat[16][DSTR];
    __shared__ float att[16][DATT];
    __shared__ __align__(16) float Wc[CH * DSTR];
    __shared__ float px[16][10];
    __shared__ __align__(16) float agg_s[DSTR];
    __shared__ int nidx[16];

    const int bq  = blockIdx.x;
    const int b   = bq >> 14;
    const int q   = bq & (Qn - 1);
    const int tid = threadIdx.x;

    if (tid < 16) {
        const int idx = nm_cl[bq * Kn + tid];
        nidx[tid] = idx;
        const float* nb = c_q + ((size_t)b * Qn + idx) * 3;
        const float qx = c_q[bq * 3 + 0], qy = c_q[bq * 3 + 1], qz = c_q[bq * 3 + 2];
        const float nx = nb[0], ny = nb[1], nz = nb[2];
        const float rx = qx - nx, ry = qy - ny, rz = qz - nz;
        px[tid][0] = sqrtf(rx * rx + ry * ry + rz * rz);
        px[tid][1] = rx; px[tid][2] = ry; px[tid][3] = rz;
        px[tid][4] = qx; px[tid][5] = qy; px[tid][6] = qz;
        px[tid][7] = nx; px[tid][8] = ny; px[tid][9] = nz;
    }
    if (tid < 32) fhat[tid >> 1][DATT + (tid & 1)] = 0.f;
    __syncthreads();

    if (tid < 160) {
        const int r = tid / 10, o = tid - r * 10;
        float y = 0.f;
        #pragma unroll
        for (int c = 0; c < 10; ++c) y += px[r][c] * W_cl[o * 10 + c];
        y = (y - m_cl[o]) * (g_cl[o] * rsqrtf(v_cl[o] + EPSF)) + b_cl[o];
        fhat[r][o] = fmaxf(y, 0.f);
    }
    // gather f_tilde rows (f_cur)
    for (int i = tid; i < Kn * DLB; i += 256) {
        const int r = i >> 7, c = i & 127;
        fhat[r][10 + c] = f_tilde[((size_t)b * Qn + nidx[r]) * DLB + c];
    }

    // att2 = fhat @ W_fc2^T, chunked; one row per thread-group row
    const int tr = tid >> 4, tc = tid & 15;
    for (int chunk = 0; chunk < 3; ++chunk) {
        __syncthreads();
        const float* Wsrc = W_fc2 + chunk * CH * DATT;
        for (int i = tid; i < CH * DSTR; i += 256) {
            const int o = i / DSTR, c = i - o * DSTR;
            Wc[i] = (c < DATT) ? Wsrc[o * DATT + c] : 0.f;
        }
        __syncthreads();
        float acc[3] = {0.f, 0.f, 0.f};
        for (int c = 0; c < DSTR; c += 4) {
            const float4 a = *(const float4*)&fhat[tr][c];
            #pragma unroll
            for (int j = 0; j < 3; ++j) {
                const int ol = tc + 16 * j;
                if (ol < CH) {
                    const float4 w = *(const float4*)&Wc[ol * DSTR + c];
                    acc[j] += a.x * w.x + a.y * w.y + a.z * w.z + a.w * w.w;
                }
            }
        }
        #pragma unroll
        for (int j = 0; j < 3; ++j) {
            const int ol = tc + 16 * j;
            if (ol < CH) att[tr][chunk * CH + ol] = acc[j];
        }
    }
    __syncthreads();

    if (tid < DSTR) {
        if (tid < DATT) {
            float mx = -1e30f;
            for (int r = 0; r < 16; ++r) mx = fmaxf(mx, att[r][tid]);
            float s = 0.f, a = 0.f;
            for (int r = 0; r < 16; ++r) {
                const float e = expf(att[r][tid] - mx);
                s += e;
                a += fhat[r][tid] * e;
            }
            agg_s[tid] = a / s;
        } else {
            agg_s[tid] = 0.f;
        }
    }

    for (int chunk = 0; chunk < 3; ++chunk) {
        __syncthreads();
        const int o0 = chunk * CH;
        const int nrows = (o0 + CH <= DLB) ? CH : (DLB - o0);
        const float* Wsrc = W_mlp2 + o0 * DATT;
        for (int i = tid; i < nrows * DSTR; i += 256) {
            const int o = i / DSTR, c = i - o * DSTR;
            Wc[i] = (c < DATT) ? Wsrc[o * DATT + c] : 0.f;
        }
        __syncthreads();
        if (tid < nrows) {
            const int o = o0 + tid;
            float y = 0.f;
            for (int c = 0; c < DSTR; c += 4) {
                const float4 w = *(const float4*)&Wc[tid * DSTR + c];
                const float4 a = *(const float4*)&agg_s[c];
                y += a.x * w.x + a.y * w.y + a.z * w.z + a.w * w.w;
            }
            y = (y - m2[o]) * (g2[o] * rsqrtf(v2[o] + EPSF)) + b2[o];
            // output layout (B, 128, Q, 1)
            out[((size_t)(b * DLB + o) << 14) + q] = fmaxf(y, 0.f);
        }
    }
}

extern "C" void kernel_launch(void* const* d_in, const int* in_sizes, int n_in,
                              void* d_out, int out_size, void* d_ws, size_t ws_size,
                              hipStream_t stream)
{
    const float* feat_lb = (const float*)d_in[0];
    const float* feat_sc = (const float*)d_in[1];
    const int*   nm_lb   = (const int*)d_in[2];
    const int*   nm_sc   = (const int*)d_in[3];
    const float* c_lb    = (const float*)d_in[4];
    const float* c_sc    = (const float*)d_in[5];
    const float* c_q     = (const float*)d_in[6];
    const int*   nm_cl   = (const int*)d_in[7];
    const float* W_lb = (const float*)d_in[8];
    const float* g_lb = (const float*)d_in[9];
    const float* b_lb = (const float*)d_in[10];
    const float* m_lb = (const float*)d_in[11];
    const float* v_lb = (const float*)d_in[12];
    const float* W_sc = (const float*)d_in[13];
    const float* g_sc = (const float*)d_in[14];
    const float* b_sc = (const float*)d_in[15];
    const float* m_sc = (const float*)d_in[16];
    const float* v_sc = (const float*)d_in[17];
    const float* W_fc1  = (const float*)d_in[18];
    const float* W_mlp1 = (const float*)d_in[19];
    const float* g1 = (const float*)d_in[20];
    const float* b1 = (const float*)d_in[21];
    const float* m1 = (const float*)d_in[22];
    const float* v1 = (const float*)d_in[23];
    const float* W_cl = (const float*)d_in[24];
    const float* g_cl = (const float*)d_in[25];
    const float* b_cl = (const float*)d_in[26];
    const float* m_cl = (const float*)d_in[27];
    const float* v_cl = (const float*)d_in[28];
    const float* W_fc2  = (const float*)d_in[29];
    const float* W_mlp2 = (const float*)d_in[30];
    const float* g2 = (const float*)d_in[31];
    const float* b2 = (const float*)d_in[32];
    const float* m2 = (const float*)d_in[33];
    const float* v2 = (const float*)d_in[34];

    float* f_tilde = (float*)d_ws;       // B*Q*128 floats = 16 MB
    float* out = (float*)d_out;          // (B,128,Q,1) f32

    dim3 grid(2 * Qn), block(256);
    hipLaunchKernelGGL(stage1, grid, block, 0, stream,
        feat_lb, feat_sc, nm_lb, nm_sc, c_lb, c_sc, c_q,
        W_lb, g_lb, b_lb, m_lb, v_lb,
        W_sc, g_sc, b_sc, m_sc, v_sc,
        W_fc1, W_mlp1, g1, b1, m1, v1, f_tilde);
    hipLaunchKernelGGL(stage2, grid, block, 0, stream,
        nm_cl, c_q, W_cl, g_cl, b_cl, m_cl, v_cl,
        W_fc2, W_mlp2, g2, b2, m2, v2, f_tilde, out);
}

// Round 2
// 430.189 us; speedup vs baseline: 12.1595x; 12.1595x over previous
//
#include <hip/hip_runtime.h>
#include <cmath>

#define EPSF 1e-5f
typedef unsigned int  uint32;
typedef unsigned short ushort16;
typedef __attribute__((ext_vector_type(8))) short bfrag;   // 8 bf16 = 4 VGPRs
typedef __attribute__((ext_vector_type(4))) float f32x4;

constexpr int Qn   = 16384;
constexpr int DATT = 138;
constexpr int KS   = 168;    // LDS K stride (bf16 elems): 336 B rows -> 2-way banks
constexpr int Nd   = 4096;

// ws layout (in bf16 elements)
constexpr int OFF_W1  = 0;            // W_fc1 tiled  [9*5 tiles][64 lanes][8]
constexpr int LEN_W1  = 9 * 5 * 512;  // 23040
constexpr int OFF_WM1 = OFF_W1 + LEN_W1;           // 23040
constexpr int LEN_WM1 = 8 * 5 * 512;  // 20480
constexpr int OFF_W2  = OFF_WM1 + LEN_WM1;         // 43520
constexpr int LEN_W2  = 9 * 5 * 512;
constexpr int OFF_WM2 = OFF_W2 + LEN_W2;           // 66560
constexpr int LEN_WM2 = 8 * 5 * 512;
constexpr int OFF_FT  = OFF_WM2 + LEN_WM2;         // 87040 (byte off 174080, 16B aligned)
constexpr int PREP_N  = OFF_FT;                    // 87040 converted weight elems

__device__ __forceinline__ unsigned short f2b(float f) {
    uint32 u = __float_as_uint(f);
    uint32 r = (u + 0x7fffu + ((u >> 16) & 1u)) >> 16;
    return (unsigned short)r;
}
__device__ __forceinline__ float b2f(unsigned short h) {
    return __uint_as_float(((uint32)h) << 16);
}
__device__ __forceinline__ uint32 pack2(float x, float y) {
    return (uint32)f2b(x) | ((uint32)f2b(y) << 16);
}

// ---------------- weight pre-conversion to fragment-linear bf16 ----------------
__global__ __launch_bounds__(256) void prep_weights(
    const float* __restrict__ Wfc1, const float* __restrict__ Wmlp1,
    const float* __restrict__ Wfc2, const float* __restrict__ Wmlp2,
    unsigned short* __restrict__ ws16)
{
    int i = blockIdx.x * 256 + threadIdx.x;
    if (i >= PREP_N) return;
    const float* src; int nrows; int idx;
    if (i < OFF_WM1)      { src = Wfc1;  nrows = DATT; idx = i - OFF_W1; }
    else if (i < OFF_W2)  { src = Wmlp1; nrows = 128;  idx = i - OFF_WM1; }
    else if (i < OFF_WM2) { src = Wfc2;  nrows = DATT; idx = i - OFF_W2; }
    else                  { src = Wmlp2; nrows = 128;  idx = i - OFF_WM2; }
    int t    = idx >> 9;          // tile = nt*5 + kt
    int lane = (idx >> 3) & 63;
    int j    = idx & 7;
    int nt = t / 5, kt = t - nt * 5;
    int row = nt * 16 + (lane & 15);
    int k   = kt * 32 + ((lane >> 4) << 3) + j;
    float v = (row < nrows && k < DATT) ? src[row * DATT + k] : 0.f;
    ws16[i] = f2b(v);
}

// ---------------- Stage 1: 4 queries/block ----------------
__global__ __launch_bounds__(256, 3) void stage1(
    const float* __restrict__ feat_lb, const float* __restrict__ feat_sc,
    const int* __restrict__ nm_lb, const int* __restrict__ nm_sc,
    const float* __restrict__ c_lb, const float* __restrict__ c_sc,
    const float* __restrict__ c_q,
    const float* __restrict__ W_lb, const float* __restrict__ g_lb,
    const float* __restrict__ b_lb, const float* __restrict__ m_lb, const float* __restrict__ v_lb,
    const float* __restrict__ W_sc, const float* __restrict__ g_sc,
    const float* __restrict__ b_sc, const float* __restrict__ m_sc, const float* __restrict__ v_sc,
    const float* __restrict__ g1, const float* __restrict__ b1,
    const float* __restrict__ m1, const float* __restrict__ v1,
    const unsigned short* __restrict__ ws16)
{
    __shared__ __align__(16) unsigned short fhat[128 * KS];     // 43008 B
    __shared__ __align__(16) float pxu[128 * 10];               // 5120 B, overlaid by aggs
    unsigned short* aggs = (unsigned short*)pxu;                // [16][160] bf16

    const int tid  = threadIdx.x;
    const int bq0  = blockIdx.x * 4;         // composite b*Q+q, 4 queries
    const int b    = bq0 >> 14;
    const int lane = tid & 63;
    const int w    = tid >> 6;               // wave = query
    const int lrow = lane & 15;
    const int lgr  = lane >> 4;

    const unsigned short* W1t  = ws16 + OFF_W1;
    const unsigned short* Wm1t = ws16 + OFF_WM1;
    unsigned short* ft = (unsigned short*)(ws16 + OFF_FT);

    // ---- features -> fhat (bf16) ----
    {
        const float2* flb = (const float2*)(feat_lb + (size_t)bq0 * 2048);
        for (int u = tid; u < 4096; u += 256) {
            float2 v = flb[u];
            int q = u >> 10, rem = u & 1023;
            int r = rem >> 6, c2 = rem & 63;
            *(uint32*)&fhat[(q * 32 + r) * KS + 10 + c2 * 2] = pack2(v.x, v.y);
        }
        const float2* fsc = (const float2*)(feat_sc + (size_t)bq0 * 1024);
        for (int u = tid; u < 2048; u += 256) {
            float2 v = fsc[u];
            int q = u >> 9, rem = u & 511;
            int r = rem >> 5, c2 = rem & 31;
            *(uint32*)&fhat[(q * 32 + 16 + r) * KS + 74 + c2 * 2] = pack2(v.x, v.y);
        }
        for (int u = tid; u < 128 * 15; u += 256) {  // zero pad cols 138..167
            int row = u / 15, c2 = u - row * 15;
            *(uint32*)&fhat[row * KS + 138 + c2 * 2] = 0u;
        }
    }
    // ---- rel-pos 10-vectors ----
    if (tid < 128) {
        const int q = tid >> 5, r = tid & 31;
        const int bq = bq0 + q;
        const bool lb = r < 16;
        const int idx = lb ? nm_lb[bq * 16 + r] : nm_sc[bq * 16 + (r - 16)];
        const float* nb = lb ? (c_lb + ((size_t)b * Nd + idx) * 3)
                             : (c_sc + ((size_t)b * Qn + idx) * 3);
        const float qx = c_q[bq * 3 + 0], qy = c_q[bq * 3 + 1], qz = c_q[bq * 3 + 2];
        const float nx = nb[0], ny = nb[1], nz = nb[2];
        const float rx = qx - nx, ry = qy - ny, rz = qz - nz;
        float* px = pxu + tid * 10;
        px[0] = sqrtf(rx * rx + ry * ry + rz * rz);
        px[1] = rx; px[2] = ry; px[3] = rz;
        px[4] = qx; px[5] = qy; px[6] = qz;
        px[7] = nx; px[8] = ny; px[9] = nz;
    }
    __syncthreads();

    // ---- small convs + BN + relu -> fhat ----
    for (int i = tid; i < 640; i += 256) {      // lb: 64 rows x 10 out
        int qr = i / 10, o = i - qr * 10;
        int q = qr >> 4, r = qr & 15;
        const float* px = pxu + (q * 32 + r) * 10;
        float y = 0.f;
        #pragma unroll
        for (int c = 0; c < 10; ++c) y += px[c] * W_lb[o * 10 + c];
        y = (y - m_lb[o]) * (g_lb[o] * rsqrtf(v_lb[o] + EPSF)) + b_lb[o];
        fhat[(q * 32 + r) * KS + o] = f2b(fmaxf(y, 0.f));
    }
    for (int i = tid; i < 4736; i += 256) {     // sc: 64 rows x 74 out
        int qr = i / 74, o = i - qr * 74;
        int q = qr >> 4, r = qr & 15;
        const float* px = pxu + (q * 32 + 16 + r) * 10;
        float y = 0.f;
        #pragma unroll
        for (int c = 0; c < 10; ++c) y += px[c] * W_sc[o * 10 + c];
        y = (y - m_sc[o]) * (g_sc[o] * rsqrtf(v_sc[o] + EPSF)) + b_sc[o];
        fhat[(q * 32 + 16 + r) * KS + o] = f2b(fmaxf(y, 0.f));
    }
    __syncthreads();

    // ---- per-wave: att GEMM (32x160 @ 160x144) + softmax + agg ----
    bfrag af[2][5];
    #pragma unroll
    for (int mt = 0; mt < 2; ++mt)
        #pragma unroll
        for (int kt = 0; kt < 5; ++kt)
            af[mt][kt] = *(const bfrag*)&fhat[(w * 32 + mt * 16 + lrow) * KS + kt * 32 + lgr * 8];

    const f32x4 zf = {0.f, 0.f, 0.f, 0.f};
    f32x4 acc[9][2];
    #pragma unroll
    for (int nt = 0; nt < 9; ++nt) { acc[nt][0] = zf; acc[nt][1] = zf; }

    #pragma unroll
    for (int nt = 0; nt < 9; ++nt) {
        #pragma unroll
        for (int kt = 0; kt < 5; ++kt) {
            bfrag bf = *(const bfrag*)&W1t[((nt * 5 + kt) << 9) + (lane << 3)];
            acc[nt][0] = __builtin_amdgcn_mfma_f32_16x16x32_bf16(af[0][kt], bf, acc[nt][0], 0, 0, 0);
            acc[nt][1] = __builtin_amdgcn_mfma_f32_16x16x32_bf16(af[1][kt], bf, acc[nt][1], 0, 0, 0);
        }
    }

    #pragma unroll
    for (int nt = 0; nt < 9; ++nt) {
        const int ch = nt * 16 + lrow;
        float mx = acc[nt][0][0];
        #pragma unroll
        for (int r = 1; r < 4; ++r) mx = fmaxf(mx, acc[nt][0][r]);
        #pragma unroll
        for (int r = 0; r < 4; ++r) mx = fmaxf(mx, acc[nt][1][r]);
        mx = fmaxf(mx, __shfl_xor(mx, 16));
        mx = fmaxf(mx, __shfl_xor(mx, 32));
        float s = 0.f, num = 0.f;
        #pragma unroll
        for (int mt = 0; mt < 2; ++mt)
            #pragma unroll
            for (int r = 0; r < 4; ++r) {
                float e = __expf(acc[nt][mt][r] - mx);
                s += e;
                float fh = b2f(fhat[(w * 32 + mt * 16 + lgr * 4 + r) * KS + ch]);
                num += e * fh;
            }
        s   += __shfl_xor(s, 16);   s   += __shfl_xor(s, 32);
        num += __shfl_xor(num, 16); num += __shfl_xor(num, 32);
        if (lane < 16) {
            float val = (ch < DATT) ? (num / s) : 0.f;
            aggs[w * 160 + ch] = f2b(val);
        }
    }
    if (lane < 16) aggs[w * 160 + 144 + lane] = 0;
    __syncthreads();

    // ---- MLP 160->128 (M=4 queries) ----
    bfrag am[5];
    #pragma unroll
    for (int kt = 0; kt < 5; ++kt)
        am[kt] = *(const bfrag*)&aggs[lrow * 160 + kt * 32 + lgr * 8];
    #pragma unroll
    for (int oi = 0; oi < 2; ++oi) {
        const int ot = w * 2 + oi;
        f32x4 c = zf;
        #pragma unroll
        for (int kt = 0; kt < 5; ++kt) {
            bfrag bf = *(const bfrag*)&Wm1t[((ot * 5 + kt) << 9) + (lane << 3)];
            c = __builtin_amdgcn_mfma_f32_16x16x32_bf16(am[kt], bf, c, 0, 0, 0);
        }
        if (lgr == 0) {
            const int o = ot * 16 + lrow;
            const float sc = g1[o] * rsqrtf(v1[o] + EPSF);
            const float mm = m1[o], bb = b1[o];
            #pragma unroll
            for (int r = 0; r < 4; ++r) {
                float y = (c[r] - mm) * sc + bb;
                ft[(size_t)(bq0 + r) * 128 + o] = f2b(fmaxf(y, 0.f));
            }
        }
    }
}

// ---------------- Stage 2: 8 queries/block ----------------
__global__ __launch_bounds__(256, 3) void stage2(
    const int* __restrict__ nm_cl, const float* __restrict__ c_q,
    const float* __restrict__ W_cl, const float* __restrict__ g_cl,
    const float* __restrict__ b_cl, const float* __restrict__ m_cl, const float* __restrict__ v_cl,
    const float* __restrict__ g2, const float* __restrict__ b2,
    const float* __restrict__ m2, const float* __restrict__ v2,
    const unsigned short* __restrict__ ws16, float* __restrict__ out)
{
    __shared__ __align__(16) unsigned short fhat[128 * KS];
    __shared__ __align__(16) float pxu[128 * 10];
    __shared__ int nidx[128];
    unsigned short* aggs = (unsigned short*)pxu;   // [16][160]

    const int tid  = threadIdx.x;
    const int bq0  = blockIdx.x * 8;
    const int b    = bq0 >> 14;
    const int q0   = bq0 & (Qn - 1);
    const int lane = tid & 63;
    const int w    = tid >> 6;
    const int lrow = lane & 15;
    const int lgr  = lane >> 4;

    const unsigned short* W2t  = ws16 + OFF_W2;
    const unsigned short* Wm2t = ws16 + OFF_WM2;
    const unsigned short* ft   = ws16 + OFF_FT;

    for (int u = tid; u < 128 * 15; u += 256) {    // zero pad cols 138..167
        int row = u / 15, c2 = u - row * 15;
        *(uint32*)&fhat[row * KS + 138 + c2 * 2] = 0u;
    }
    if (tid < 128) {
        const int q = tid >> 4, r = tid & 15;
        const int bq = bq0 + q;
        const int idx = nm_cl[bq * 16 + r];
        nidx[tid] = idx;
        const float* nb = c_q + ((size_t)(b << 14) + idx) * 3;
        const float qx = c_q[bq * 3 + 0], qy = c_q[bq * 3 + 1], qz = c_q[bq * 3 + 2];
        const float nx = nb[0], ny = nb[1], nz = nb[2];
        const float rx = qx - nx, ry = qy - ny, rz = qz - nz;
        float* px = pxu + tid * 10;
        px[0] = sqrtf(rx * rx + ry * ry + rz * rz);
        px[1] = rx; px[2] = ry; px[3] = rz;
        px[4] = qx; px[5] = qy; px[6] = qz;
        px[7] = nx; px[8] = ny; px[9] = nz;
    }
    __syncthreads();

    for (int i = tid; i < 1280; i += 256) {        // conv cl: 128 rows x 10
        int row = i / 10, o = i - row * 10;
        const float* px = pxu + row * 10;
        float y = 0.f;
        #pragma unroll
        for (int c = 0; c < 10; ++c) y += px[c] * W_cl[o * 10 + c];
        y = (y - m_cl[o]) * (g_cl[o] * rsqrtf(v_cl[o] + EPSF)) + b_cl[o];
        fhat[row * KS + o] = f2b(fmaxf(y, 0.f));
    }
    for (int u = tid; u < 8192; u += 256) {        // gather f_tilde (bf16 pairs)
        int q = u >> 10, rem = u & 1023;
        int r = rem >> 6, c2 = rem & 63;
        const uint32* srow = (const uint32*)(ft + (size_t)((b << 14) + nidx[q * 16 + r]) * 128);
        *(uint32*)&fhat[(q * 16 + r) * KS + 10 + c2 * 2] = srow[c2];
    }
    __syncthreads();

    // ---- per-wave: 2 queries (2 m-tiles) ----
    bfrag af[2][5];
    #pragma unroll
    for (int mt = 0; mt < 2; ++mt)
        #pragma unroll
        for (int kt = 0; kt < 5; ++kt)
            af[mt][kt] = *(const bfrag*)&fhat[((2 * w + mt) * 16 + lrow) * KS + kt * 32 + lgr * 8];

    const f32x4 zf = {0.f, 0.f, 0.f, 0.f};
    f32x4 acc[9][2];
    #pragma unroll
    for (int nt = 0; nt < 9; ++nt) { acc[nt][0] = zf; acc[nt][1] = zf; }

    #pragma unroll
    for (int nt = 0; nt < 9; ++nt) {
        #pragma unroll
        for (int kt = 0; kt < 5; ++kt) {
            bfrag bf = *(const bfrag*)&W2t[((nt * 5 + kt) << 9) + (lane << 3)];
            acc[nt][0] = __builtin_amdgcn_mfma_f32_16x16x32_bf16(af[0][kt], bf, acc[nt][0], 0, 0, 0);
            acc[nt][1] = __builtin_amdgcn_mfma_f32_16x16x32_bf16(af[1][kt], bf, acc[nt][1], 0, 0, 0);
        }
    }

    #pragma unroll
    for (int mt = 0; mt < 2; ++mt) {
        const int qq = 2 * w + mt;
        #pragma unroll
        for (int nt = 0; nt < 9; ++nt) {
            const int ch = nt * 16 + lrow;
            float mx = acc[nt][mt][0];
            #pragma unroll
            for (int r = 1; r < 4; ++r) mx = fmaxf(mx, acc[nt][mt][r]);
            mx = fmaxf(mx, __shfl_xor(mx, 16));
            mx = fmaxf(mx, __shfl_xor(mx, 32));
            float s = 0.f, num = 0.f;
            #pragma unroll
            for (int r = 0; r < 4; ++r) {
                float e = __expf(acc[nt][mt][r] - mx);
                s += e;
                float fh = b2f(fhat[(qq * 16 + lgr * 4 + r) * KS + ch]);
                num += e * fh;
            }
            s   += __shfl_xor(s, 16);   s   += __shfl_xor(s, 32);
            num += __shfl_xor(num, 16); num += __shfl_xor(num, 32);
            if (lane < 16) {
                float val = (ch < DATT) ? (num / s) : 0.f;
                aggs[qq * 160 + ch] = f2b(val);
            }
        }
        if (lane < 16) aggs[qq * 160 + 144 + lane] = 0;
    }
    __syncthreads();

    // ---- MLP 160->128 (M=8 queries) -> out (B,128,Q,1) f32 ----
    bfrag am[5];
    #pragma unroll
    for (int kt = 0; kt < 5; ++kt)
        am[kt] = *(const bfrag*)&aggs[lrow * 160 + kt * 32 + lgr * 8];
    #pragma unroll
    for (int oi = 0; oi < 2; ++oi) {
        const int ot = w * 2 + oi;
        f32x4 c = zf;
        #pragma unroll
        for (int kt = 0; kt < 5; ++kt) {
            bfrag bf = *(const bfrag*)&Wm2t[((ot * 5 + kt) << 9) + (lane << 3)];
            c = __builtin_amdgcn_mfma_f32_16x16x32_bf16(am[kt], bf, c, 0, 0, 0);
        }
        if (lgr < 2) {
            const int o = ot * 16 + lrow;
            const float sc = g2[o] * rsqrtf(v2[o] + EPSF);
            const float mm = m2[o], bb = b2[o];
            #pragma unroll
            for (int r = 0; r < 4; ++r) {
                const int qloc = lgr * 4 + r;
                float y = (c[r] - mm) * sc + bb;
                out[((size_t)(b * 128 + o) << 14) + q0 + qloc] = fmaxf(y, 0.f);
            }
        }
    }
}

extern "C" void kernel_launch(void* const* d_in, const int* in_sizes, int n_in,
                              void* d_out, int out_size, void* d_ws, size_t ws_size,
                              hipStream_t stream)
{
    const float* feat_lb = (const float*)d_in[0];
    const float* feat_sc = (const float*)d_in[1];
    const int*   nm_lb   = (const int*)d_in[2];
    const int*   nm_sc   = (const int*)d_in[3];
    const float* c_lb    = (const float*)d_in[4];
    const float* c_sc    = (const float*)d_in[5];
    const float* c_q     = (const float*)d_in[6];
    const int*   nm_cl   = (const int*)d_in[7];
    const float* W_lb = (const float*)d_in[8];
    const float* g_lb = (const float*)d_in[9];
    const float* b_lb = (const float*)d_in[10];
    const float* m_lb = (const float*)d_in[11];
    const float* v_lb = (const float*)d_in[12];
    const float* W_sc = (const float*)d_in[13];
    const float* g_sc = (const float*)d_in[14];
    const float* b_sc = (const float*)d_in[15];
    const float* m_sc = (const float*)d_in[16];
    const float* v_sc = (const float*)d_in[17];
    const float* W_fc1  = (const float*)d_in[18];
    const float* W_mlp1 = (const float*)d_in[19];
    const float* g1 = (const float*)d_in[20];
    const float* b1 = (const float*)d_in[21];
    const float* m1 = (const float*)d_in[22];
    const float* v1 = (const float*)d_in[23];
    const float* W_cl = (const float*)d_in[24];
    const float* g_cl = (const float*)d_in[25];
    const float* b_cl = (const float*)d_in[26];
    const float* m_cl = (const float*)d_in[27];
    const float* v_cl = (const float*)d_in[28];
    const float* W_fc2  = (const float*)d_in[29];
    const float* W_mlp2 = (const float*)d_in[30];
    const float* g2 = (const float*)d_in[31];
    const float* b2 = (const float*)d_in[32];
    const float* m2 = (const float*)d_in[33];
    const float* v2 = (const float*)d_in[34];

    unsigned short* ws16 = (unsigned short*)d_ws;
    float* out = (float*)d_out;

    hipLaunchKernelGGL(prep_weights, dim3((PREP_N + 255) / 256), dim3(256), 0, stream,
        W_fc1, W_mlp1, W_fc2, W_mlp2, ws16);

    hipLaunchKernelGGL(stage1, dim3(2 * Qn / 4), dim3(256), 0, stream,
        feat_lb, feat_sc, nm_lb, nm_sc, c_lb, c_sc, c_q,
        W_lb, g_lb, b_lb, m_lb, v_lb,
        W_sc, g_sc, b_sc, m_sc, v_sc,
        g1, b1, m1, v1, ws16);

    hipLaunchKernelGGL(stage2, dim3(2 * Qn / 8), dim3(256), 0, stream,
        nm_cl, c_q, W_cl, g_cl, b_cl, m_cl, v_cl,
        g2, b2, m2, v2, ws16, out);
}

// Round 3
// 332.767 us; speedup vs baseline: 15.7194x; 1.2928x over previous
//
#include <hip/hip_runtime.h>
#include <cmath>

#define EPSF 1e-5f
typedef unsigned int  uint32;
typedef unsigned short u16;
typedef __attribute__((ext_vector_type(8))) short bfrag;   // 8 bf16 = 4 VGPRs
typedef __attribute__((ext_vector_type(4))) float f32x4;

constexpr int Qn   = 16384;
constexpr int KS   = 168;    // fhat K stride (bf16 elems) = 336 B
constexpr int PXS  = 40;     // px stride (bf16 elems) = 80 B
constexpr int Nd   = 4096;

// ws layout (bf16 elements). K remap for att/mlp: k' = k<10 ? k : k+2 (140 used, pad 160)
constexpr int OFF_W1  = 0;                 // W_fc1  9 nt x 5 kt x 512
constexpr int OFF_WM1 = 23040;             // W_mlp1 8 x 5 x 512
constexpr int OFF_W2  = 43520;             // W_fc2
constexpr int OFF_WM2 = 66560;             // W_mlp2
constexpr int OFF_WLB = 87040;             // W_lb   1 tile (16x32)
constexpr int OFF_WSC = 87552;             // W_sc   5 tiles
constexpr int OFF_WCL = 90112;             // W_cl   1 tile
constexpr int OFF_FT  = 90624;             // f_tilde bf16 [2*Q][128]
constexpr int PREP_N  = OFF_FT;

__device__ __forceinline__ u16 f2b(float f) {
    uint32 u = __float_as_uint(f);
    uint32 r = (u + 0x7fffu + ((u >> 16) & 1u)) >> 16;
    return (u16)r;
}
__device__ __forceinline__ float b2f(u16 h) {
    return __uint_as_float(((uint32)h) << 16);
}
__device__ __forceinline__ uint32 pack2(float x, float y) {
    return (uint32)f2b(x) | ((uint32)f2b(y) << 16);
}

// ---------------- weight pre-conversion to fragment-linear bf16 ----------------
__global__ __launch_bounds__(256) void prep_weights(
    const float* __restrict__ Wfc1, const float* __restrict__ Wmlp1,
    const float* __restrict__ Wfc2, const float* __restrict__ Wmlp2,
    const float* __restrict__ Wlb,  const float* __restrict__ Wsc,
    const float* __restrict__ Wcl,  u16* __restrict__ ws16)
{
    int i = blockIdx.x * 256 + threadIdx.x;
    if (i >= PREP_N) return;
    int lane = (i >> 3) & 63, j = i & 7;
    int row16 = lane & 15;
    int kf = ((lane >> 4) << 3) + j;      // 0..31 within k-tile
    float v = 0.f;
    if (i < OFF_WLB) {                    // att / mlp weights, K remapped
        const float* src; int nrows; int idx;
        if (i < OFF_WM1)      { src = Wfc1;  nrows = 138; idx = i - OFF_W1; }
        else if (i < OFF_W2)  { src = Wmlp1; nrows = 128; idx = i - OFF_WM1; }
        else if (i < OFF_WM2) { src = Wfc2;  nrows = 138; idx = i - OFF_W2; }
        else                  { src = Wmlp2; nrows = 128; idx = i - OFF_WM2; }
        int t = idx >> 9, nt = t / 5, kt = t - nt * 5;
        int row = nt * 16 + row16;
        int kp  = kt * 32 + kf;
        int k   = (kp < 10) ? kp : kp - 2;
        if (row < nrows && kp < 140 && kp != 10 && kp != 11) v = src[row * 138 + k];
    } else {                              // conv weights, K = 10 (pad 32), no remap
        const float* src; int nrows; int idx;
        if (i < OFF_WSC)      { src = Wlb; nrows = 10; idx = i - OFF_WLB; }
        else if (i < OFF_WCL) { src = Wsc; nrows = 74; idx = i - OFF_WSC; }
        else                  { src = Wcl; nrows = 10; idx = i - OFF_WCL; }
        int t = idx >> 9;
        int row = t * 16 + row16;
        if (row < nrows && kf < 10) v = src[row * 10 + kf];
    }
    ws16[i] = f2b(v);
}

// ---------------- Stage 1: 4 queries/block ----------------
__global__ __launch_bounds__(256, 3) void stage1(
    const float* __restrict__ feat_lb, const float* __restrict__ feat_sc,
    const int* __restrict__ nm_lb, const int* __restrict__ nm_sc,
    const float* __restrict__ c_lb, const float* __restrict__ c_sc,
    const float* __restrict__ c_q,
    const float* __restrict__ g_lb, const float* __restrict__ b_lb,
    const float* __restrict__ m_lb, const float* __restrict__ v_lb,
    const float* __restrict__ g_sc, const float* __restrict__ b_sc,
    const float* __restrict__ m_sc, const float* __restrict__ v_sc,
    const float* __restrict__ g1, const float* __restrict__ b1,
    const float* __restrict__ m1, const float* __restrict__ v1,
    u16* __restrict__ ws16)
{
    __shared__ __align__(16) u16 fhat[128 * KS];     // 43008 B
    __shared__ __align__(16) u16 pxs[128 * PXS];     // 10240 B, overlaid by aggs
    u16* aggs = pxs;                                  // [16][160] bf16

    const int tid  = threadIdx.x;
    const int bq0  = blockIdx.x * 4;
    const int b    = bq0 >> 14;
    const int lane = tid & 63;
    const int w    = tid >> 6;               // wave = query
    const int lrow = lane & 15;
    const int lgr  = lane >> 4;

    const u16* W1t  = ws16 + OFF_W1;
    const u16* Wm1t = ws16 + OFF_WM1;
    const u16* WLB  = ws16 + OFF_WLB;
    const u16* WSC  = ws16 + OFF_WSC;
    u16* ft = ws16 + OFF_FT;

    // ---- writers: features -> fhat (cols 12.. / 76..), zero pads, px ----
    {
        const float4* flb = (const float4*)(feat_lb + (size_t)bq0 * 2048);
        for (int u = tid; u < 2048; u += 256) {
            float4 v = flb[u];
            int q = u >> 9, rem = u & 511, r = rem >> 5, c4 = rem & 31;
            uint32* d = (uint32*)&fhat[(q * 32 + r) * KS + 12 + c4 * 4];
            d[0] = pack2(v.x, v.y); d[1] = pack2(v.z, v.w);
        }
        const float4* fsc = (const float4*)(feat_sc + (size_t)bq0 * 1024);
        for (int u = tid; u < 1024; u += 256) {
            float4 v = fsc[u];
            int q = u >> 8, rem = u & 255, r = rem >> 4, c4 = rem & 15;
            uint32* d = (uint32*)&fhat[(q * 32 + 16 + r) * KS + 76 + c4 * 4];
            d[0] = pack2(v.x, v.y); d[1] = pack2(v.z, v.w);
        }
        for (int u = tid; u < 128 * 15; u += 256) {   // zero cols 10,11 and 140..167
            int row = u / 15, jj = u - row * 15;
            uint32* base = (uint32*)((char*)fhat + row * 336);
            if (jj == 0) base[5] = 0u; else base[69 + jj] = 0u;
        }
    }
    if (tid < 128) {
        const int q = tid >> 5, r = tid & 31;
        const int bq = bq0 + q;
        const bool lb = r < 16;
        const int idx = lb ? nm_lb[bq * 16 + r] : nm_sc[bq * 16 + (r - 16)];
        const float* nb = lb ? (c_lb + ((size_t)b * Nd + idx) * 3)
                             : (c_sc + ((size_t)b * Qn + idx) * 3);
        const float qx = c_q[bq * 3 + 0], qy = c_q[bq * 3 + 1], qz = c_q[bq * 3 + 2];
        const float nx = nb[0], ny = nb[1], nz = nb[2];
        const float rx = qx - nx, ry = qy - ny, rz = qz - nz;
        const float dd = sqrtf(rx * rx + ry * ry + rz * rz);
        uint32* pw = (uint32*)&pxs[tid * PXS];
        pw[0] = pack2(dd, rx); pw[1] = pack2(ry, rz); pw[2] = pack2(qx, qy);
        pw[3] = pack2(qz, nx); pw[4] = pack2(ny, nz);
        #pragma unroll
        for (int z = 5; z < 20; ++z) pw[z] = 0u;
    }
    __syncthreads();

    const f32x4 zf = {0.f, 0.f, 0.f, 0.f};

    // ---- convs via MFMA: lb (1 tile) + sc (5 tiles) ----
    {
        bfrag pa0 = *(const bfrag*)&pxs[(w * 32 + lrow) * PXS + lgr * 8];
        bfrag pa1 = *(const bfrag*)&pxs[(w * 32 + 16 + lrow) * PXS + lgr * 8];
        {
            bfrag bw = *(const bfrag*)&WLB[lane << 3];
            f32x4 c = __builtin_amdgcn_mfma_f32_16x16x32_bf16(pa0, bw, zf, 0, 0, 0);
            if (lrow < 10) {
                const int o = lrow;
                const float sc_ = g_lb[o] * rsqrtf(v_lb[o] + EPSF);
                const float sh  = b_lb[o] - m_lb[o] * sc_;
                #pragma unroll
                for (int r = 0; r < 4; ++r)
                    fhat[(w * 32 + lgr * 4 + r) * KS + o] = f2b(fmaxf(c[r] * sc_ + sh, 0.f));
            }
        }
        #pragma unroll
        for (int nt = 0; nt < 5; ++nt) {
            bfrag bw = *(const bfrag*)&WSC[(nt << 9) + (lane << 3)];
            f32x4 c = __builtin_amdgcn_mfma_f32_16x16x32_bf16(pa1, bw, zf, 0, 0, 0);
            const int o = nt * 16 + lrow;
            if (o < 74) {
                const float sc_ = g_sc[o] * rsqrtf(v_sc[o] + EPSF);
                const float sh  = b_sc[o] - m_sc[o] * sc_;
                const int cp = (o < 10) ? o : o + 2;
                #pragma unroll
                for (int r = 0; r < 4; ++r)
                    fhat[(w * 32 + 16 + lgr * 4 + r) * KS + cp] = f2b(fmaxf(c[r] * sc_ + sh, 0.f));
            }
        }
    }
    __syncthreads();

    // ---- att GEMM (32x160 @ 160x144) + softmax over 32 rows + agg ----
    bfrag af[2][5];
    #pragma unroll
    for (int mt = 0; mt < 2; ++mt)
        #pragma unroll
        for (int kt = 0; kt < 5; ++kt)
            af[mt][kt] = *(const bfrag*)&fhat[(w * 32 + mt * 16 + lrow) * KS + kt * 32 + lgr * 8];

    f32x4 acc[9][2];
    #pragma unroll
    for (int nt = 0; nt < 9; ++nt) { acc[nt][0] = zf; acc[nt][1] = zf; }
    #pragma unroll
    for (int nt = 0; nt < 9; ++nt) {
        #pragma unroll
        for (int kt = 0; kt < 5; ++kt) {
            bfrag bf = *(const bfrag*)&W1t[((nt * 5 + kt) << 9) + (lane << 3)];
            acc[nt][0] = __builtin_amdgcn_mfma_f32_16x16x32_bf16(af[0][kt], bf, acc[nt][0], 0, 0, 0);
            acc[nt][1] = __builtin_amdgcn_mfma_f32_16x16x32_bf16(af[1][kt], bf, acc[nt][1], 0, 0, 0);
        }
    }

    #pragma unroll
    for (int nt = 0; nt < 9; ++nt) {
        const int ch  = nt * 16 + lrow;
        const int chp = ch + (ch >= 10 ? 2 : 0);
        float mx = acc[nt][0][0];
        #pragma unroll
        for (int r = 1; r < 4; ++r) mx = fmaxf(mx, acc[nt][0][r]);
        #pragma unroll
        for (int r = 0; r < 4; ++r) mx = fmaxf(mx, acc[nt][1][r]);
        mx = fmaxf(mx, __shfl_xor(mx, 16));
        mx = fmaxf(mx, __shfl_xor(mx, 32));
        float s = 0.f, num = 0.f;
        #pragma unroll
        for (int mt = 0; mt < 2; ++mt)
            #pragma unroll
            for (int r = 0; r < 4; ++r) {
                float e = __expf(acc[nt][mt][r] - mx);
                s += e;
                num += e * b2f(fhat[(w * 32 + mt * 16 + lgr * 4 + r) * KS + chp]);
            }
        s   += __shfl_xor(s, 16);   s   += __shfl_xor(s, 32);
        num += __shfl_xor(num, 16); num += __shfl_xor(num, 32);
        if (lane < 16) aggs[w * 160 + chp] = f2b((ch < 138) ? (num / s) : 0.f);
    }
    if (lane < 14) aggs[w * 160 + 146 + lane] = 0;
    if (lane < 2)  aggs[w * 160 + 10 + lane] = 0;
    __syncthreads();

    // ---- MLP 160->128 ----
    bfrag am[5];
    #pragma unroll
    for (int kt = 0; kt < 5; ++kt)
        am[kt] = *(const bfrag*)&aggs[lrow * 160 + kt * 32 + lgr * 8];
    #pragma unroll
    for (int oi = 0; oi < 2; ++oi) {
        const int ot = w * 2 + oi;
        f32x4 c = zf;
        #pragma unroll
        for (int kt = 0; kt < 5; ++kt) {
            bfrag bf = *(const bfrag*)&Wm1t[((ot * 5 + kt) << 9) + (lane << 3)];
            c = __builtin_amdgcn_mfma_f32_16x16x32_bf16(am[kt], bf, c, 0, 0, 0);
        }
        if (lgr == 0) {
            const int o = ot * 16 + lrow;
            const float sc_ = g1[o] * rsqrtf(v1[o] + EPSF);
            const float sh  = b1[o] - m1[o] * sc_;
            #pragma unroll
            for (int r = 0; r < 4; ++r)
                ft[(size_t)(bq0 + r) * 128 + o] = f2b(fmaxf(c[r] * sc_ + sh, 0.f));
        }
    }
}

// ---------------- Stage 2: 8 queries/block ----------------
__global__ __launch_bounds__(256, 3) void stage2(
    const int* __restrict__ nm_cl, const float* __restrict__ c_q,
    const float* __restrict__ g_cl, const float* __restrict__ b_cl,
    const float* __restrict__ m_cl, const float* __restrict__ v_cl,
    const float* __restrict__ g2, const float* __restrict__ b2,
    const float* __restrict__ m2, const float* __restrict__ v2,
    const u16* __restrict__ ws16, float* __restrict__ out)
{
    __shared__ __align__(16) u16 fhat[128 * KS];
    __shared__ __align__(16) u16 pxs[128 * PXS];
    u16* aggs = pxs;

    const int tid  = threadIdx.x;
    const int bq0  = blockIdx.x * 8;
    const int b    = bq0 >> 14;
    const int q0   = bq0 & (Qn - 1);
    const int lane = tid & 63;
    const int w    = tid >> 6;
    const int lrow = lane & 15;
    const int lgr  = lane >> 4;

    const u16* W2t  = ws16 + OFF_W2;
    const u16* Wm2t = ws16 + OFF_WM2;
    const u16* WCL  = ws16 + OFF_WCL;
    const u16* ft   = ws16 + OFF_FT;

    for (int u = tid; u < 128 * 15; u += 256) {       // zero cols 10,11 and 140..167
        int row = u / 15, jj = u - row * 15;
        uint32* base = (uint32*)((char*)fhat + row * 336);
        if (jj == 0) base[5] = 0u; else base[69 + jj] = 0u;
    }
    if (tid < 128) {
        const int q = tid >> 4, r = tid & 15;
        const int bq = bq0 + q;
        const int idx = nm_cl[bq * 16 + r];
        const float* nb = c_q + ((size_t)(b << 14) + idx) * 3;
        const float qx = c_q[bq * 3 + 0], qy = c_q[bq * 3 + 1], qz = c_q[bq * 3 + 2];
        const float nx = nb[0], ny = nb[1], nz = nb[2];
        const float rx = qx - nx, ry = qy - ny, rz = qz - nz;
        const float dd = sqrtf(rx * rx + ry * ry + rz * rz);
        uint32* pw = (uint32*)&pxs[tid * PXS];
        pw[0] = pack2(dd, rx); pw[1] = pack2(ry, rz); pw[2] = pack2(qx, qy);
        pw[3] = pack2(qz, nx); pw[4] = pack2(ny, nz);
        #pragma unroll
        for (int z = 5; z < 20; ++z) pw[z] = 0u;
    }
    // gather f_tilde rows -> fhat cols 12..139 (bf16 u32 pairs)
    for (int u = tid; u < 8192; u += 256) {
        int row = u >> 6, c2 = u & 63;
        int idx = nm_cl[bq0 * 16 + row];
        const uint32* srow = (const uint32*)(ft + (size_t)((b << 14) + idx) * 128);
        *(uint32*)&fhat[row * KS + 12 + c2 * 2] = srow[c2];
    }
    __syncthreads();

    const f32x4 zf = {0.f, 0.f, 0.f, 0.f};

    // ---- conv cl via MFMA (2 m-tiles per wave) ----
    {
        bfrag bw = *(const bfrag*)&WCL[lane << 3];
        #pragma unroll
        for (int mt = 0; mt < 2; ++mt) {
            bfrag pa = *(const bfrag*)&pxs[(w * 32 + mt * 16 + lrow) * PXS + lgr * 8];
            f32x4 c = __builtin_amdgcn_mfma_f32_16x16x32_bf16(pa, bw, zf, 0, 0, 0);
            if (lrow < 10) {
                const int o = lrow;
                const float sc_ = g_cl[o] * rsqrtf(v_cl[o] + EPSF);
                const float sh  = b_cl[o] - m_cl[o] * sc_;
                #pragma unroll
                for (int r = 0; r < 4; ++r)
                    fhat[(w * 32 + mt * 16 + lgr * 4 + r) * KS + o] = f2b(fmaxf(c[r] * sc_ + sh, 0.f));
            }
        }
    }
    __syncthreads();

    // ---- att GEMM + per-query softmax over 16 rows + agg ----
    bfrag af[2][5];
    #pragma unroll
    for (int mt = 0; mt < 2; ++mt)
        #pragma unroll
        for (int kt = 0; kt < 5; ++kt)
            af[mt][kt] = *(const bfrag*)&fhat[((2 * w + mt) * 16 + lrow) * KS + kt * 32 + lgr * 8];

    f32x4 acc[9][2];
    #pragma unroll
    for (int nt = 0; nt < 9; ++nt) { acc[nt][0] = zf; acc[nt][1] = zf; }
    #pragma unroll
    for (int nt = 0; nt < 9; ++nt) {
        #pragma unroll
        for (int kt = 0; kt < 5; ++kt) {
            bfrag bf = *(const bfrag*)&W2t[((nt * 5 + kt) << 9) + (lane << 3)];
            acc[nt][0] = __builtin_amdgcn_mfma_f32_16x16x32_bf16(af[0][kt], bf, acc[nt][0], 0, 0, 0);
            acc[nt][1] = __builtin_amdgcn_mfma_f32_16x16x32_bf16(af[1][kt], bf, acc[nt][1], 0, 0, 0);
        }
    }

    #pragma unroll
    for (int mt = 0; mt < 2; ++mt) {
        const int qq = 2 * w + mt;
        #pragma unroll
        for (int nt = 0; nt < 9; ++nt) {
            const int ch  = nt * 16 + lrow;
            const int chp = ch + (ch >= 10 ? 2 : 0);
            float mx = acc[nt][mt][0];
            #pragma unroll
            for (int r = 1; r < 4; ++r) mx = fmaxf(mx, acc[nt][mt][r]);
            mx = fmaxf(mx, __shfl_xor(mx, 16));
            mx = fmaxf(mx, __shfl_xor(mx, 32));
            float s = 0.f, num = 0.f;
            #pragma unroll
            for (int r = 0; r < 4; ++r) {
                float e = __expf(acc[nt][mt][r] - mx);
                s += e;
                num += e * b2f(fhat[(qq * 16 + lgr * 4 + r) * KS + chp]);
            }
            s   += __shfl_xor(s, 16);   s   += __shfl_xor(s, 32);
            num += __shfl_xor(num, 16); num += __shfl_xor(num, 32);
            if (lane < 16) aggs[qq * 160 + chp] = f2b((ch < 138) ? (num / s) : 0.f);
        }
        if (lane < 14) aggs[qq * 160 + 146 + lane] = 0;
        if (lane < 2)  aggs[qq * 160 + 10 + lane] = 0;
    }
    __syncthreads();

    // ---- MLP 160->128 -> out (B,128,Q,1) ----
    bfrag am[5];
    #pragma unroll
    for (int kt = 0; kt < 5; ++kt)
        am[kt] = *(const bfrag*)&aggs[lrow * 160 + kt * 32 + lgr * 8];
    #pragma unroll
    for (int oi = 0; oi < 2; ++oi) {
        const int ot = w * 2 + oi;
        f32x4 c = zf;
        #pragma unroll
        for (int kt = 0; kt < 5; ++kt) {
            bfrag bf = *(const bfrag*)&Wm2t[((ot * 5 + kt) << 9) + (lane << 3)];
            c = __builtin_amdgcn_mfma_f32_16x16x32_bf16(am[kt], bf, c, 0, 0, 0);
        }
        if (lgr < 2) {
            const int o = ot * 16 + lrow;
            const float sc_ = g2[o] * rsqrtf(v2[o] + EPSF);
            const float sh  = b2[o] - m2[o] * sc_;
            #pragma unroll
            for (int r = 0; r < 4; ++r) {
                const int qloc = lgr * 4 + r;
                out[((size_t)(b * 128 + o) << 14) + q0 + qloc] = fmaxf(c[r] * sc_ + sh, 0.f);
            }
        }
    }
}

extern "C" void kernel_launch(void* const* d_in, const int* in_sizes, int n_in,
                              void* d_out, int out_size, void* d_ws, size_t ws_size,
                              hipStream_t stream)
{
    const float* feat_lb = (const float*)d_in[0];
    const float* feat_sc = (const float*)d_in[1];
    const int*   nm_lb   = (const int*)d_in[2];
    const int*   nm_sc   = (const int*)d_in[3];
    const float* c_lb    = (const float*)d_in[4];
    const float* c_sc    = (const float*)d_in[5];
    const float* c_q     = (const float*)d_in[6];
    const int*   nm_cl   = (const int*)d_in[7];
    const float* W_lb = (const float*)d_in[8];
    const float* g_lb = (const float*)d_in[9];
    const float* b_lb = (const float*)d_in[10];
    const float* m_lb = (const float*)d_in[11];
    const float* v_lb = (const float*)d_in[12];
    const float* W_sc = (const float*)d_in[13];
    const float* g_sc = (const float*)d_in[14];
    const float* b_sc = (const float*)d_in[15];
    const float* m_sc = (const float*)d_in[16];
    const float* v_sc = (const float*)d_in[17];
    const float* W_fc1  = (const float*)d_in[18];
    const float* W_mlp1 = (const float*)d_in[19];
    const float* g1 = (const float*)d_in[20];
    const float* b1 = (const float*)d_in[21];
    const float* m1 = (const float*)d_in[22];
    const float* v1 = (const float*)d_in[23];
    const float* W_cl = (const float*)d_in[24];
    const float* g_cl = (const float*)d_in[25];
    const float* b_cl = (const float*)d_in[26];
    const float* m_cl = (const float*)d_in[27];
    const float* v_cl = (const float*)d_in[28];
    const float* W_fc2  = (const float*)d_in[29];
    const float* W_mlp2 = (const float*)d_in[30];
    const float* g2 = (const float*)d_in[31];
    const float* b2 = (const float*)d_in[32];
    const float* m2 = (const float*)d_in[33];
    const float* v2 = (const float*)d_in[34];

    u16* ws16 = (u16*)d_ws;
    float* out = (float*)d_out;

    hipLaunchKernelGGL(prep_weights, dim3((PREP_N + 255) / 256), dim3(256), 0, stream,
        W_fc1, W_mlp1, W_fc2, W_mlp2, W_lb, W_sc, W_cl, ws16);

    hipLaunchKernelGGL(stage1, dim3(2 * Qn / 4), dim3(256), 0, stream,
        feat_lb, feat_sc, nm_lb, nm_sc, c_lb, c_sc, c_q,
        g_lb, b_lb, m_lb, v_lb, g_sc, b_sc, m_sc, v_sc,
        g1, b1, m1, v1, ws16);

    hipLaunchKernelGGL(stage2, dim3(2 * Qn / 8), dim3(256), 0, stream,
        nm_cl, c_q, g_cl, b_cl, m_cl, v_cl,
        g2, b2, m2, v2, ws16, out);
}

// Round 4
// 325.270 us; speedup vs baseline: 16.0817x; 1.0230x over previous
//
#include <hip/hip_runtime.h>
#include <cmath>

#define EPSF 1e-5f
typedef unsigned int  uint32;
typedef unsigned short u16;
typedef __attribute__((ext_vector_type(8))) short bfrag;   // 8 bf16 = 4 VGPRs
typedef __attribute__((ext_vector_type(4))) float f32x4;

constexpr int Qn   = 16384;
constexpr int KS   = 168;    // fhat K stride (bf16 elems) = 336 B
constexpr int PXS  = 40;     // px stride (bf16 elems) = 80 B
constexpr int Nd   = 4096;

// ws layout (bf16 elements). K remap for att/mlp: k' = k<10 ? k : k+2
constexpr int OFF_W1  = 0;                 // W_fc1  9 nt x 5 kt x 512
constexpr int OFF_WM1 = 23040;             // W_mlp1 8 x 5 x 512
constexpr int OFF_W2  = 43520;             // W_fc2
constexpr int OFF_WM2 = 66560;             // W_mlp2
constexpr int OFF_WLB = 87040;             // W_lb   1 tile
constexpr int OFF_WSC = 87552;             // W_sc   5 tiles
constexpr int OFF_WCL = 90112;             // W_cl   1 tile
constexpr int END_W   = 90624;
// BN (scale,shift) f32 pairs at byte 181248 (16B aligned); indices in f32 elems
constexpr int BN_LB = 0;                   // 10 pairs
constexpr int BN_SC = 20;                  // 74 pairs
constexpr int BN_CL = 168;                 // 10 pairs
constexpr int BN_M1 = 188;                 // 128 pairs
constexpr int BN_M2 = 444;                 // 128 pairs
constexpr int BN_TOT = 700;
constexpr int OFF_FT  = END_W + 2 * BN_TOT;   // 92024 (u16), byte 184048
constexpr int PREP_N  = END_W + BN_TOT;

__device__ __forceinline__ u16 f2b(float f) {
    uint32 u = __float_as_uint(f);
    uint32 r = (u + 0x7fffu + ((u >> 16) & 1u)) >> 16;
    return (u16)r;
}
__device__ __forceinline__ float b2f(u16 h) {
    return __uint_as_float(((uint32)h) << 16);
}
// packed f32->bf16 via HW instruction: D.lo = bf16(a), D.hi = bf16(b)
__device__ __forceinline__ uint32 cvtpk(float a, float b) {
    uint32 r;
    asm("v_cvt_pk_bf16_f32 %0, %1, %2" : "=v"(r) : "v"(a), "v"(b));
    return r;
}
__device__ __forceinline__ u16 cvt1(float a) { return (u16)cvtpk(a, a); }

// ---------------- weight pre-conversion + BN pair precompute ----------------
__global__ __launch_bounds__(256) void prep_weights(
    const float* __restrict__ Wfc1, const float* __restrict__ Wmlp1,
    const float* __restrict__ Wfc2, const float* __restrict__ Wmlp2,
    const float* __restrict__ Wlb,  const float* __restrict__ Wsc,
    const float* __restrict__ Wcl,
    const float* __restrict__ g_lb, const float* __restrict__ b_lb,
    const float* __restrict__ m_lb, const float* __restrict__ v_lb,
    const float* __restrict__ g_sc, const float* __restrict__ b_sc,
    const float* __restrict__ m_sc, const float* __restrict__ v_sc,
    const float* __restrict__ g_cl, const float* __restrict__ b_cl,
    const float* __restrict__ m_cl, const float* __restrict__ v_cl,
    const float* __restrict__ g1, const float* __restrict__ b1,
    const float* __restrict__ m1, const float* __restrict__ v1,
    const float* __restrict__ g2, const float* __restrict__ b2,
    const float* __restrict__ m2, const float* __restrict__ v2,
    u16* __restrict__ ws16)
{
    int i = blockIdx.x * 256 + threadIdx.x;
    if (i >= PREP_N) return;
    if (i >= END_W) {                      // BN pairs
        int j = i - END_W;
        const float *g, *bb, *m, *v; int o2;
        if (j < BN_SC)      { g = g_lb; bb = b_lb; m = m_lb; v = v_lb; o2 = j - BN_LB; }
        else if (j < BN_CL) { g = g_sc; bb = b_sc; m = m_sc; v = v_sc; o2 = j - BN_SC; }
        else if (j < BN_M1) { g = g_cl; bb = b_cl; m = m_cl; v = v_cl; o2 = j - BN_CL; }
        else if (j < BN_M2) { g = g1;   bb = b1;   m = m1;   v = v1;   o2 = j - BN_M1; }
        else                { g = g2;   bb = b2;   m = m2;   v = v2;   o2 = j - BN_M2; }
        int o = o2 >> 1;
        float sc_ = g[o] * rsqrtf(v[o] + EPSF);
        ((float*)(ws16 + END_W))[j] = (o2 & 1) ? (bb[o] - m[o] * sc_) : sc_;
        return;
    }
    int lane = (i >> 3) & 63, jj = i & 7;
    int row16 = lane & 15;
    int kf = ((lane >> 4) << 3) + jj;
    float v = 0.f;
    if (i < OFF_WLB) {                    // att / mlp weights, K remapped
        const float* src; int nrows; int idx;
        if (i < OFF_WM1)      { src = Wfc1;  nrows = 138; idx = i - OFF_W1; }
        else if (i < OFF_W2)  { src = Wmlp1; nrows = 128; idx = i - OFF_WM1; }
        else if (i < OFF_WM2) { src = Wfc2;  nrows = 138; idx = i - OFF_W2; }
        else                  { src = Wmlp2; nrows = 128; idx = i - OFF_WM2; }
        int t = idx >> 9, nt = t / 5, kt = t - nt * 5;
        int row = nt * 16 + row16;
        int kp  = kt * 32 + kf;
        int k   = (kp < 10) ? kp : kp - 2;
        if (row < nrows && kp < 140 && kp != 10 && kp != 11) v = src[row * 138 + k];
    } else {                              // conv weights, K = 10 (pad 32)
        const float* src; int nrows; int idx;
        if (i < OFF_WSC)      { src = Wlb; nrows = 10; idx = i - OFF_WLB; }
        else if (i < OFF_WCL) { src = Wsc; nrows = 74; idx = i - OFF_WSC; }
        else                  { src = Wcl; nrows = 10; idx = i - OFF_WCL; }
        int t = idx >> 9;
        int row = t * 16 + row16;
        if (row < nrows && kf < 10) v = src[row * 10 + kf];
    }
    ws16[i] = f2b(v);
}

// ---------------- Stage 1: 4 queries/block ----------------
__global__ __launch_bounds__(256, 3) void stage1(
    const float* __restrict__ feat_lb, const float* __restrict__ feat_sc,
    const int* __restrict__ nm_lb, const int* __restrict__ nm_sc,
    const float* __restrict__ c_lb, const float* __restrict__ c_sc,
    const float* __restrict__ c_q,
    u16* __restrict__ ws16)
{
    __shared__ __align__(16) u16 fhat[128 * KS];     // 43008 B
    __shared__ __align__(16) u16 pxs[128 * PXS];     // 10240 B, overlaid by aggs
    u16* aggs = pxs;                                  // [4 used rows][160] bf16

    const int tid  = threadIdx.x;
    const int bq0  = blockIdx.x * 4;
    const int b    = bq0 >> 14;
    const int lane = tid & 63;
    const int w    = tid >> 6;               // wave = query
    const int lrow = lane & 15;
    const int lgr  = lane >> 4;

    const u16* W1t  = ws16 + OFF_W1;
    const u16* Wm1t = ws16 + OFF_WM1;
    const float* bn = (const float*)(ws16 + END_W);
    u16* ft = ws16 + OFF_FT;

    // ---- hoisted conv weights + BN pairs (latency hides under staging) ----
    bfrag wlb = *(const bfrag*)&ws16[OFF_WLB + (lane << 3)];
    bfrag wsc[5];
    #pragma unroll
    for (int nt = 0; nt < 5; ++nt)
        wsc[nt] = *(const bfrag*)&ws16[OFF_WSC + (nt << 9) + (lane << 3)];
    float2 bnlb = {0.f, 0.f};
    if (lrow < 10) bnlb = *(const float2*)&bn[BN_LB + lrow * 2];
    float2 bnsc[5];
    #pragma unroll
    for (int nt = 0; nt < 5; ++nt) {
        int o = nt * 16 + lrow;
        bnsc[nt] = (o < 74) ? *(const float2*)&bn[BN_SC + o * 2] : float2{0.f, 0.f};
    }

    // ---- features -> fhat (bf16), zero pads, px ----
    {
        const float4* flb = (const float4*)(feat_lb + (size_t)bq0 * 2048);
        for (int u = tid; u < 2048; u += 256) {
            float4 v = flb[u];
            int q = u >> 9, rem = u & 511, r = rem >> 5, c4 = rem & 31;
            uint32* d = (uint32*)&fhat[(q * 32 + r) * KS + 12 + c4 * 4];
            d[0] = cvtpk(v.x, v.y); d[1] = cvtpk(v.z, v.w);
        }
        const float4* fsc = (const float4*)(feat_sc + (size_t)bq0 * 1024);
        for (int u = tid; u < 1024; u += 256) {
            float4 v = fsc[u];
            int q = u >> 8, rem = u & 255, r = rem >> 4, c4 = rem & 15;
            uint32* d = (uint32*)&fhat[(q * 32 + 16 + r) * KS + 76 + c4 * 4];
            d[0] = cvtpk(v.x, v.y); d[1] = cvtpk(v.z, v.w);
        }
        for (int u = tid; u < 128 * 15; u += 256) {   // zero cols 10,11 and 140..167
            int row = u / 15, jj = u - row * 15;
            uint32* base = (uint32*)((char*)fhat + row * 336);
            if (jj == 0) base[5] = 0u; else base[69 + jj] = 0u;
        }
    }
    if (tid < 128) {
        const int q = tid >> 5, r = tid & 31;
        const int bq = bq0 + q;
        const bool lb = r < 16;
        const int idx = lb ? nm_lb[bq * 16 + r] : nm_sc[bq * 16 + (r - 16)];
        const float* nb = lb ? (c_lb + ((size_t)b * Nd + idx) * 3)
                             : (c_sc + ((size_t)b * Qn + idx) * 3);
        const float qx = c_q[bq * 3 + 0], qy = c_q[bq * 3 + 1], qz = c_q[bq * 3 + 2];
        const float nx = nb[0], ny = nb[1], nz = nb[2];
        const float rx = qx - nx, ry = qy - ny, rz = qz - nz;
        const float dd = sqrtf(rx * rx + ry * ry + rz * rz);
        uint32* pw = (uint32*)&pxs[tid * PXS];
        pw[0] = cvtpk(dd, rx); pw[1] = cvtpk(ry, rz); pw[2] = cvtpk(qx, qy);
        pw[3] = cvtpk(qz, nx); pw[4] = cvtpk(ny, nz);
        #pragma unroll
        for (int z = 5; z < 20; ++z) pw[z] = 0u;
    }
    __syncthreads();

    const f32x4 zf = {0.f, 0.f, 0.f, 0.f};

    // ---- convs via MFMA: lb (1 tile) + sc (5 tiles) ----
    {
        bfrag pa0 = *(const bfrag*)&pxs[(w * 32 + lrow) * PXS + lgr * 8];
        bfrag pa1 = *(const bfrag*)&pxs[(w * 32 + 16 + lrow) * PXS + lgr * 8];
        {
            f32x4 c = __builtin_amdgcn_mfma_f32_16x16x32_bf16(pa0, wlb, zf, 0, 0, 0);
            if (lrow < 10) {
                #pragma unroll
                for (int r = 0; r < 4; ++r)
                    fhat[(w * 32 + lgr * 4 + r) * KS + lrow] = cvt1(fmaxf(c[r] * bnlb.x + bnlb.y, 0.f));
            }
        }
        #pragma unroll
        for (int nt = 0; nt < 5; ++nt) {
            f32x4 c = __builtin_amdgcn_mfma_f32_16x16x32_bf16(pa1, wsc[nt], zf, 0, 0, 0);
            const int o = nt * 16 + lrow;
            if (o < 74) {
                const int cp = (o < 10) ? o : o + 2;
                #pragma unroll
                for (int r = 0; r < 4; ++r)
                    fhat[(w * 32 + 16 + lgr * 4 + r) * KS + cp] = cvt1(fmaxf(c[r] * bnsc[nt].x + bnsc[nt].y, 0.f));
            }
        }
    }
    __syncthreads();

    // ---- att GEMM (32x160 @ 160x144): all MFMAs first, then softmax ----
    bfrag af[2][5];
    #pragma unroll
    for (int mt = 0; mt < 2; ++mt)
        #pragma unroll
        for (int kt = 0; kt < 5; ++kt)
            af[mt][kt] = *(const bfrag*)&fhat[(w * 32 + mt * 16 + lrow) * KS + kt * 32 + lgr * 8];

    f32x4 acc[9][2];
    #pragma unroll
    for (int nt = 0; nt < 9; ++nt) { acc[nt][0] = zf; acc[nt][1] = zf; }
    #pragma unroll
    for (int nt = 0; nt < 9; ++nt) {
        #pragma unroll
        for (int kt = 0; kt < 5; ++kt) {
            bfrag bf = *(const bfrag*)&W1t[((nt * 5 + kt) << 9) + (lane << 3)];
            acc[nt][0] = __builtin_amdgcn_mfma_f32_16x16x32_bf16(af[0][kt], bf, acc[nt][0], 0, 0, 0);
            acc[nt][1] = __builtin_amdgcn_mfma_f32_16x16x32_bf16(af[1][kt], bf, acc[nt][1], 0, 0, 0);
        }
    }
    __builtin_amdgcn_sched_barrier(0);   // keep GEMM and softmax as separate regions

    #pragma unroll
    for (int nt = 0; nt < 9; ++nt) {
        const int ch  = nt * 16 + lrow;
        const int chp = ch + (ch >= 10 ? 2 : 0);
        float mx = acc[nt][0][0];
        #pragma unroll
        for (int r = 1; r < 4; ++r) mx = fmaxf(mx, acc[nt][0][r]);
        #pragma unroll
        for (int r = 0; r < 4; ++r) mx = fmaxf(mx, acc[nt][1][r]);
        mx = fmaxf(mx, __shfl_xor(mx, 16));
        mx = fmaxf(mx, __shfl_xor(mx, 32));
        float s = 0.f, num = 0.f;
        #pragma unroll
        for (int mt = 0; mt < 2; ++mt)
            #pragma unroll
            for (int r = 0; r < 4; ++r) {
                float e = __expf(acc[nt][mt][r] - mx);
                s += e;
                num += e * b2f(fhat[(w * 32 + mt * 16 + lgr * 4 + r) * KS + chp]);
            }
        s   += __shfl_xor(s, 16);   s   += __shfl_xor(s, 32);
        num += __shfl_xor(num, 16); num += __shfl_xor(num, 32);
        if (lane < 16) aggs[w * 160 + chp] = cvt1((ch < 138) ? (num / s) : 0.f);
    }
    if (lane < 14) aggs[w * 160 + 146 + lane] = 0;
    if (lane < 2)  aggs[w * 160 + 10 + lane] = 0;
    __syncthreads();

    // ---- MLP 160->128 ----
    bfrag am[5];
    #pragma unroll
    for (int kt = 0; kt < 5; ++kt)
        am[kt] = *(const bfrag*)&aggs[lrow * 160 + kt * 32 + lgr * 8];
    #pragma unroll
    for (int oi = 0; oi < 2; ++oi) {
        const int ot = w * 2 + oi;
        f32x4 c = zf;
        #pragma unroll
        for (int kt = 0; kt < 5; ++kt) {
            bfrag bf = *(const bfrag*)&Wm1t[((ot * 5 + kt) << 9) + (lane << 3)];
            c = __builtin_amdgcn_mfma_f32_16x16x32_bf16(am[kt], bf, c, 0, 0, 0);
        }
        if (lgr == 0) {
            const int o = ot * 16 + lrow;
            float2 p = *(const float2*)&bn[BN_M1 + o * 2];
            #pragma unroll
            for (int r = 0; r < 4; ++r)
                ft[(size_t)(bq0 + r) * 128 + o] = cvt1(fmaxf(c[r] * p.x + p.y, 0.f));
        }
    }
}

// ---------------- Stage 2: 8 queries/block ----------------
__global__ __launch_bounds__(256, 3) void stage2(
    const int* __restrict__ nm_cl, const float* __restrict__ c_q,
    const u16* __restrict__ ws16, float* __restrict__ out)
{
    __shared__ __align__(16) u16 fhat[128 * KS];
    __shared__ __align__(16) u16 pxs[128 * PXS];
    u16* aggs = pxs;

    const int tid  = threadIdx.x;
    const int bq0  = blockIdx.x * 8;
    const int b    = bq0 >> 14;
    const int q0   = bq0 & (Qn - 1);
    const int lane = tid & 63;
    const int w    = tid >> 6;
    const int lrow = lane & 15;
    const int lgr  = lane >> 4;

    const u16* W2t  = ws16 + OFF_W2;
    const u16* Wm2t = ws16 + OFF_WM2;
    const float* bn = (const float*)(ws16 + END_W);
    const u16* ft   = ws16 + OFF_FT;

    // hoisted conv weight + BN pair
    bfrag wcl = *(const bfrag*)&ws16[OFF_WCL + (lane << 3)];
    float2 bncl = {0.f, 0.f};
    if (lrow < 10) bncl = *(const float2*)&bn[BN_CL + lrow * 2];

    for (int u = tid; u < 128 * 15; u += 256) {       // zero cols 10,11 and 140..167
        int row = u / 15, jj = u - row * 15;
        uint32* base = (uint32*)((char*)fhat + row * 336);
        if (jj == 0) base[5] = 0u; else base[69 + jj] = 0u;
    }
    if (tid < 128) {
        const int q = tid >> 4, r = tid & 15;
        const int bq = bq0 + q;
        const int idx = nm_cl[bq * 16 + r];
        const float* nb = c_q + ((size_t)(b << 14) + idx) * 3;
        const float qx = c_q[bq * 3 + 0], qy = c_q[bq * 3 + 1], qz = c_q[bq * 3 + 2];
        const float nx = nb[0], ny = nb[1], nz = nb[2];
        const float rx = qx - nx, ry = qy - ny, rz = qz - nz;
        const float dd = sqrtf(rx * rx + ry * ry + rz * rz);
        uint32* pw = (uint32*)&pxs[tid * PXS];
        pw[0] = cvtpk(dd, rx); pw[1] = cvtpk(ry, rz); pw[2] = cvtpk(qx, qy);
        pw[3] = cvtpk(qz, nx); pw[4] = cvtpk(ny, nz);
        #pragma unroll
        for (int z = 5; z < 20; ++z) pw[z] = 0u;
    }
    // gather f_tilde rows -> fhat cols 12..139 (bf16 u32 pairs)
    for (int u = tid; u < 8192; u += 256) {
        int row = u >> 6, c2 = u & 63;
        int idx = nm_cl[bq0 * 16 + row];
        const uint32* srow = (const uint32*)(ft + (size_t)((b << 14) + idx) * 128);
        *(uint32*)&fhat[row * KS + 12 + c2 * 2] = srow[c2];
    }
    __syncthreads();

    const f32x4 zf = {0.f, 0.f, 0.f, 0.f};

    // ---- conv cl via MFMA (2 m-tiles per wave) ----
    {
        #pragma unroll
        for (int mt = 0; mt < 2; ++mt) {
            bfrag pa = *(const bfrag*)&pxs[(w * 32 + mt * 16 + lrow) * PXS + lgr * 8];
            f32x4 c = __builtin_amdgcn_mfma_f32_16x16x32_bf16(pa, wcl, zf, 0, 0, 0);
            if (lrow < 10) {
                #pragma unroll
                for (int r = 0; r < 4; ++r)
                    fhat[(w * 32 + mt * 16 + lgr * 4 + r) * KS + lrow] = cvt1(fmaxf(c[r] * bncl.x + bncl.y, 0.f));
            }
        }
    }
    __syncthreads();

    // ---- att GEMM: all MFMAs, then softmax ----
    bfrag af[2][5];
    #pragma unroll
    for (int mt = 0; mt < 2; ++mt)
        #pragma unroll
        for (int kt = 0; kt < 5; ++kt)
            af[mt][kt] = *(const bfrag*)&fhat[((2 * w + mt) * 16 + lrow) * KS + kt * 32 + lgr * 8];

    f32x4 acc[9][2];
    #pragma unroll
    for (int nt = 0; nt < 9; ++nt) { acc[nt][0] = zf; acc[nt][1] = zf; }
    #pragma unroll
    for (int nt = 0; nt < 9; ++nt) {
        #pragma unroll
        for (int kt = 0; kt < 5; ++kt) {
            bfrag bf = *(const bfrag*)&W2t[((nt * 5 + kt) << 9) + (lane << 3)];
            acc[nt][0] = __builtin_amdgcn_mfma_f32_16x16x32_bf16(af[0][kt], bf, acc[nt][0], 0, 0, 0);
            acc[nt][1] = __builtin_amdgcn_mfma_f32_16x16x32_bf16(af[1][kt], bf, acc[nt][1], 0, 0, 0);
        }
    }
    __builtin_amdgcn_sched_barrier(0);

    #pragma unroll
    for (int mt = 0; mt < 2; ++mt) {
        const int qq = 2 * w + mt;
        #pragma unroll
        for (int nt = 0; nt < 9; ++nt) {
            const int ch  = nt * 16 + lrow;
            const int chp = ch + (ch >= 10 ? 2 : 0);
            float mx = acc[nt][mt][0];
            #pragma unroll
            for (int r = 1; r < 4; ++r) mx = fmaxf(mx, acc[nt][mt][r]);
            mx = fmaxf(mx, __shfl_xor(mx, 16));
            mx = fmaxf(mx, __shfl_xor(mx, 32));
            float s = 0.f, num = 0.f;
            #pragma unroll
            for (int r = 0; r < 4; ++r) {
                float e = __expf(acc[nt][mt][r] - mx);
                s += e;
                num += e * b2f(fhat[(qq * 16 + lgr * 4 + r) * KS + chp]);
            }
            s   += __shfl_xor(s, 16);   s   += __shfl_xor(s, 32);
            num += __shfl_xor(num, 16); num += __shfl_xor(num, 32);
            if (lane < 16) aggs[qq * 160 + chp] = cvt1((ch < 138) ? (num / s) : 0.f);
        }
        if (lane < 14) aggs[qq * 160 + 146 + lane] = 0;
        if (lane < 2)  aggs[qq * 160 + 10 + lane] = 0;
    }
    __syncthreads();

    // ---- MLP 160->128 -> out (B,128,Q,1) ----
    bfrag am[5];
    #pragma unroll
    for (int kt = 0; kt < 5; ++kt)
        am[kt] = *(const bfrag*)&aggs[lrow * 160 + kt * 32 + lgr * 8];
    #pragma unroll
    for (int oi = 0; oi < 2; ++oi) {
        const int ot = w * 2 + oi;
        f32x4 c = zf;
        #pragma unroll
        for (int kt = 0; kt < 5; ++kt) {
            bfrag bf = *(const bfrag*)&Wm2t[((ot * 5 + kt) << 9) + (lane << 3)];
            c = __builtin_amdgcn_mfma_f32_16x16x32_bf16(am[kt], bf, c, 0, 0, 0);
        }
        if (lgr < 2) {
            const int o = ot * 16 + lrow;
            float2 p = *(const float2*)&bn[BN_M2 + o * 2];
            #pragma unroll
            for (int r = 0; r < 4; ++r) {
                const int qloc = lgr * 4 + r;
                out[((size_t)(b * 128 + o) << 14) + q0 + qloc] = fmaxf(c[r] * p.x + p.y, 0.f);
            }
        }
    }
}

extern "C" void kernel_launch(void* const* d_in, const int* in_sizes, int n_in,
                              void* d_out, int out_size, void* d_ws, size_t ws_size,
                              hipStream_t stream)
{
    const float* feat_lb = (const float*)d_in[0];
    const float* feat_sc = (const float*)d_in[1];
    const int*   nm_lb   = (const int*)d_in[2];
    const int*   nm_sc   = (const int*)d_in[3];
    const float* c_lb    = (const float*)d_in[4];
    const float* c_sc    = (const float*)d_in[5];
    const float* c_q     = (const float*)d_in[6];
    const int*   nm_cl   = (const int*)d_in[7];
    const float* W_lb = (const float*)d_in[8];
    const float* g_lb = (const float*)d_in[9];
    const float* b_lb = (const float*)d_in[10];
    const float* m_lb = (const float*)d_in[11];
    const float* v_lb = (const float*)d_in[12];
    const float* W_sc = (const float*)d_in[13];
    const float* g_sc = (const float*)d_in[14];
    const float* b_sc = (const float*)d_in[15];
    const float* m_sc = (const float*)d_in[16];
    const float* v_sc = (const float*)d_in[17];
    const float* W_fc1  = (const float*)d_in[18];
    const float* W_mlp1 = (const float*)d_in[19];
    const float* g1 = (const float*)d_in[20];
    const float* b1 = (const float*)d_in[21];
    const float* m1 = (const float*)d_in[22];
    const float* v1 = (const float*)d_in[23];
    const float* W_cl = (const float*)d_in[24];
    const float* g_cl = (const float*)d_in[25];
    const float* b_cl = (const float*)d_in[26];
    const float* m_cl = (const float*)d_in[27];
    const float* v_cl = (const float*)d_in[28];
    const float* W_fc2  = (const float*)d_in[29];
    const float* W_mlp2 = (const float*)d_in[30];
    const float* g2 = (const float*)d_in[31];
    const float* b2 = (const float*)d_in[32];
    const float* m2 = (const float*)d_in[33];
    const float* v2 = (const float*)d_in[34];

    u16* ws16 = (u16*)d_ws;
    float* out = (float*)d_out;

    hipLaunchKernelGGL(prep_weights, dim3((PREP_N + 255) / 256), dim3(256), 0, stream,
        W_fc1, W_mlp1, W_fc2, W_mlp2, W_lb, W_sc, W_cl,
        g_lb, b_lb, m_lb, v_lb, g_sc, b_sc, m_sc, v_sc,
        g_cl, b_cl, m_cl, v_cl, g1, b1, m1, v1, g2, b2, m2, v2, ws16);

    hipLaunchKernelGGL(stage1, dim3(2 * Qn / 4), dim3(256), 0, stream,
        feat_lb, feat_sc, nm_lb, nm_sc, c_lb, c_sc, c_q, ws16);

    hipLaunchKernelGGL(stage2, dim3(2 * Qn / 8), dim3(256), 0, stream,
        nm_cl, c_q, ws16, out);
}

// Round 5
// 230.780 us; speedup vs baseline: 22.6661x; 1.4094x over previous
//
#include <hip/hip_runtime.h>
#include <cmath>

#define EPSF 1e-5f
typedef unsigned int  uint32;
typedef unsigned short u16;
typedef __attribute__((ext_vector_type(8))) short bfrag;   // 8 bf16 = 4 VGPRs
typedef __attribute__((ext_vector_type(4))) float f32x4;

constexpr int Qn   = 16384;
constexpr int KS   = 168;    // fhat K stride (bf16 elems) = 336 B
constexpr int PXS  = 40;     // px stride (bf16 elems) = 80 B
constexpr int Nd   = 4096;

// ws layout (bf16 elements). K remap for att/mlp: k' = k<10 ? k : k+2
constexpr int OFF_W1  = 0;                 // W_fc1  9 nt x 5 kt x 512
constexpr int OFF_WM1 = 23040;             // W_mlp1 8 x 5 x 512
constexpr int OFF_W2  = 43520;             // W_fc2
constexpr int OFF_WM2 = 66560;             // W_mlp2
constexpr int OFF_WLB = 87040;             // W_lb   1 tile
constexpr int OFF_WSC = 87552;             // W_sc   5 tiles
constexpr int OFF_WCL = 90112;             // W_cl   1 tile
constexpr int END_W   = 90624;
// BN (scale,shift) f32 pairs; indices in f32 elems
constexpr int BN_LB = 0;                   // 10 pairs
constexpr int BN_SC = 20;                  // 74 pairs
constexpr int BN_CL = 168;                 // 10 pairs
constexpr int BN_M1 = 188;                 // 128 pairs
constexpr int BN_M2 = 444;                 // 128 pairs
constexpr int BN_TOT = 700;
constexpr int OFF_FT  = END_W + 2 * BN_TOT;   // u16 offset
constexpr int PREP_N  = END_W + BN_TOT;

__device__ __forceinline__ u16 f2b(float f) {
    uint32 u = __float_as_uint(f);
    uint32 r = (u + 0x7fffu + ((u >> 16) & 1u)) >> 16;
    return (u16)r;
}
__device__ __forceinline__ float b2f(u16 h) {
    return __uint_as_float(((uint32)h) << 16);
}
__device__ __forceinline__ uint32 cvtpk(float a, float b) {
    uint32 r;
    asm("v_cvt_pk_bf16_f32 %0, %1, %2" : "=v"(r) : "v"(a), "v"(b));
    return r;
}
__device__ __forceinline__ u16 cvt1(float a) { return (u16)cvtpk(a, a); }

// ---------------- weight pre-conversion + BN pair precompute ----------------
__global__ __launch_bounds__(256) void prep_weights(
    const float* __restrict__ Wfc1, const float* __restrict__ Wmlp1,
    const float* __restrict__ Wfc2, const float* __restrict__ Wmlp2,
    const float* __restrict__ Wlb,  const float* __restrict__ Wsc,
    const float* __restrict__ Wcl,
    const float* __restrict__ g_lb, const float* __restrict__ b_lb,
    const float* __restrict__ m_lb, const float* __restrict__ v_lb,
    const float* __restrict__ g_sc, const float* __restrict__ b_sc,
    const float* __restrict__ m_sc, const float* __restrict__ v_sc,
    const float* __restrict__ g_cl, const float* __restrict__ b_cl,
    const float* __restrict__ m_cl, const float* __restrict__ v_cl,
    const float* __restrict__ g1, const float* __restrict__ b1,
    const float* __restrict__ m1, const float* __restrict__ v1,
    const float* __restrict__ g2, const float* __restrict__ b2,
    const float* __restrict__ m2, const float* __restrict__ v2,
    u16* __restrict__ ws16)
{
    int i = blockIdx.x * 256 + threadIdx.x;
    if (i >= PREP_N) return;
    if (i >= END_W) {                      // BN pairs
        int j = i - END_W;
        const float *g, *bb, *m, *v; int o2;
        if (j < BN_SC)      { g = g_lb; bb = b_lb; m = m_lb; v = v_lb; o2 = j - BN_LB; }
        else if (j < BN_CL) { g = g_sc; bb = b_sc; m = m_sc; v = v_sc; o2 = j - BN_SC; }
        else if (j < BN_M1) { g = g_cl; bb = b_cl; m = m_cl; v = v_cl; o2 = j - BN_CL; }
        else if (j < BN_M2) { g = g1;   bb = b1;   m = m1;   v = v1;   o2 = j - BN_M1; }
        else                { g = g2;   bb = b2;   m = m2;   v = v2;   o2 = j - BN_M2; }
        int o = o2 >> 1;
        float sc_ = g[o] * rsqrtf(v[o] + EPSF);
        ((float*)(ws16 + END_W))[j] = (o2 & 1) ? (bb[o] - m[o] * sc_) : sc_;
        return;
    }
    int lane = (i >> 3) & 63, jj = i & 7;
    int row16 = lane & 15;
    int kf = ((lane >> 4) << 3) + jj;
    float v = 0.f;
    if (i < OFF_WLB) {                    // att / mlp weights, K remapped
        const float* src; int nrows; int idx;
        if (i < OFF_WM1)      { src = Wfc1;  nrows = 138; idx = i - OFF_W1; }
        else if (i < OFF_W2)  { src = Wmlp1; nrows = 128; idx = i - OFF_WM1; }
        else if (i < OFF_WM2) { src = Wfc2;  nrows = 138; idx = i - OFF_W2; }
        else                  { src = Wmlp2; nrows = 128; idx = i - OFF_WM2; }
        int t = idx >> 9, nt = t / 5, kt = t - nt * 5;
        int row = nt * 16 + row16;
        int kp  = kt * 32 + kf;
        int k   = (kp < 10) ? kp : kp - 2;
        if (row < nrows && kp < 140 && kp != 10 && kp != 11) v = src[row * 138 + k];
    } else {                              // conv weights, K = 10 (pad 32)
        const float* src; int nrows; int idx;
        if (i < OFF_WSC)      { src = Wlb; nrows = 10; idx = i - OFF_WLB; }
        else if (i < OFF_WCL) { src = Wsc; nrows = 74; idx = i - OFF_WSC; }
        else                  { src = Wcl; nrows = 10; idx = i - OFF_WCL; }
        int t = idx >> 9;
        int row = t * 16 + row16;
        if (row < nrows && kf < 10) v = src[row * 10 + kf];
    }
    ws16[i] = f2b(v);
}

// softmax over 32 rows (2 m-tiles) for one nt; writes aggs[q*160 + chp]
__device__ __forceinline__ void softmax32(
    const f32x4& a0, const f32x4& a1, int nt, int q,
    int lane, int lrow, int lgr, const u16* fh, u16* aggs)
{
    const int ch  = nt * 16 + lrow;
    const int chp = ch + (ch >= 10 ? 2 : 0);
    float mx = a0[0];
    #pragma unroll
    for (int r = 1; r < 4; ++r) mx = fmaxf(mx, a0[r]);
    #pragma unroll
    for (int r = 0; r < 4; ++r) mx = fmaxf(mx, a1[r]);
    mx = fmaxf(mx, __shfl_xor(mx, 16));
    mx = fmaxf(mx, __shfl_xor(mx, 32));
    float s = 0.f, num = 0.f;
    #pragma unroll
    for (int r = 0; r < 4; ++r) {
        float e = __expf(a0[r] - mx);
        s += e;
        num += e * b2f(fh[(q * 32 + lgr * 4 + r) * KS + chp]);
    }
    #pragma unroll
    for (int r = 0; r < 4; ++r) {
        float e = __expf(a1[r] - mx);
        s += e;
        num += e * b2f(fh[(q * 32 + 16 + lgr * 4 + r) * KS + chp]);
    }
    s   += __shfl_xor(s, 16);   s   += __shfl_xor(s, 32);
    num += __shfl_xor(num, 16); num += __shfl_xor(num, 32);
    if (lane < 16) aggs[q * 160 + chp] = cvt1((ch < 138) ? (num / s) : 0.f);
}

// softmax over 16 rows (1 m-tile)
__device__ __forceinline__ void softmax16(
    const f32x4& a0, int nt, int q,
    int lane, int lrow, int lgr, const u16* fh, u16* aggs)
{
    const int ch  = nt * 16 + lrow;
    const int chp = ch + (ch >= 10 ? 2 : 0);
    float mx = a0[0];
    #pragma unroll
    for (int r = 1; r < 4; ++r) mx = fmaxf(mx, a0[r]);
    mx = fmaxf(mx, __shfl_xor(mx, 16));
    mx = fmaxf(mx, __shfl_xor(mx, 32));
    float s = 0.f, num = 0.f;
    #pragma unroll
    for (int r = 0; r < 4; ++r) {
        float e = __expf(a0[r] - mx);
        s += e;
        num += e * b2f(fh[(q * 16 + lgr * 4 + r) * KS + chp]);
    }
    s   += __shfl_xor(s, 16);   s   += __shfl_xor(s, 32);
    num += __shfl_xor(num, 16); num += __shfl_xor(num, 32);
    if (lane < 16) aggs[q * 160 + chp] = cvt1((ch < 138) ? (num / s) : 0.f);
}

// ---------------- Stage 1: 4 queries/block, 8 waves, nt-partitioned ----------------
__global__ __launch_bounds__(512, 4) void stage1(
    const float* __restrict__ feat_lb, const float* __restrict__ feat_sc,
    const int* __restrict__ nm_lb, const int* __restrict__ nm_sc,
    const float* __restrict__ c_lb, const float* __restrict__ c_sc,
    const float* __restrict__ c_q,
    u16* __restrict__ ws16)
{
    __shared__ __align__(16) u16 fhat[128 * KS];     // 43008 B
    __shared__ __align__(16) u16 pxs[128 * PXS];     // 10240 B; aggs overlay
    u16* aggs = pxs;

    const int tid  = threadIdx.x;
    const int bq0  = blockIdx.x * 4;
    const int b    = bq0 >> 14;
    const int lane = tid & 63;
    const int w    = tid >> 6;               // 0..7
    const int lrow = lane & 15;
    const int lgr  = lane >> 4;

    const u16* W1t  = ws16 + OFF_W1;
    const u16* Wm1t = ws16 + OFF_WM1;
    const float* bn = (const float*)(ws16 + END_W);
    u16* ft = ws16 + OFF_FT;

    // ---- prefetch att weight frags for my nt = w (register-resident) ----
    bfrag wb[5];
    #pragma unroll
    for (int kt = 0; kt < 5; ++kt)
        wb[kt] = *(const bfrag*)&W1t[(((w * 5) + kt) << 9) + (lane << 3)];

    // ---- prefetch conv weights + BN for my conv subset ----
    const int qc = w >> 1, hc = w & 1;
    bfrag wcv[3];
    float2 bnv[3];
    if (hc == 0) {
        wcv[0] = *(const bfrag*)&ws16[OFF_WLB + (lane << 3)];
        wcv[1] = *(const bfrag*)&ws16[OFF_WSC + (lane << 3)];
        wcv[2] = *(const bfrag*)&ws16[OFF_WSC + 512 + (lane << 3)];
        bnv[0] = (lrow < 10) ? *(const float2*)&bn[BN_LB + lrow * 2] : float2{0.f, 0.f};
        bnv[1] = *(const float2*)&bn[BN_SC + lrow * 2];
        bnv[2] = *(const float2*)&bn[BN_SC + (16 + lrow) * 2];
    } else {
        #pragma unroll
        for (int t = 0; t < 3; ++t) {
            wcv[t] = *(const bfrag*)&ws16[OFF_WSC + ((2 + t) << 9) + (lane << 3)];
            int o = (2 + t) * 16 + lrow;
            bnv[t] = (o < 74) ? *(const float2*)&bn[BN_SC + o * 2] : float2{0.f, 0.f};
        }
    }

    // ---- staging: features -> fhat (bf16), zero pads, px ----
    {
        const float4* flb = (const float4*)(feat_lb + (size_t)bq0 * 2048);
        float4 r0[4];
        #pragma unroll
        for (int it = 0; it < 4; ++it) r0[it] = flb[tid + it * 512];
        const float4* fsc = (const float4*)(feat_sc + (size_t)bq0 * 1024);
        float4 r1[2];
        #pragma unroll
        for (int it = 0; it < 2; ++it) r1[it] = fsc[tid + it * 512];
        #pragma unroll
        for (int it = 0; it < 4; ++it) {
            int u = tid + it * 512;
            int q = u >> 9, rem = u & 511, r = rem >> 5, c4 = rem & 31;
            uint32* d = (uint32*)&fhat[(q * 32 + r) * KS + 12 + c4 * 4];
            d[0] = cvtpk(r0[it].x, r0[it].y); d[1] = cvtpk(r0[it].z, r0[it].w);
        }
        #pragma unroll
        for (int it = 0; it < 2; ++it) {
            int u = tid + it * 512;
            int q = u >> 8, rem = u & 255, r = rem >> 4, c4 = rem & 15;
            uint32* d = (uint32*)&fhat[(q * 32 + 16 + r) * KS + 76 + c4 * 4];
            d[0] = cvtpk(r1[it].x, r1[it].y); d[1] = cvtpk(r1[it].z, r1[it].w);
        }
        for (int u = tid; u < 128 * 15; u += 512) {   // zero cols 10,11 and 140..167
            int row = u / 15, jj = u - row * 15;
            uint32* base = (uint32*)((char*)fhat + row * 336);
            if (jj == 0) base[5] = 0u; else base[69 + jj] = 0u;
        }
    }
    if (tid < 128) {
        const int q = tid >> 5, r = tid & 31;
        const int bq = bq0 + q;
        const bool lb = r < 16;
        const int idx = lb ? nm_lb[bq * 16 + r] : nm_sc[bq * 16 + (r - 16)];
        const float* nb = lb ? (c_lb + ((size_t)b * Nd + idx) * 3)
                             : (c_sc + ((size_t)b * Qn + idx) * 3);
        const float qx = c_q[bq * 3 + 0], qy = c_q[bq * 3 + 1], qz = c_q[bq * 3 + 2];
        const float nx = nb[0], ny = nb[1], nz = nb[2];
        const float rx = qx - nx, ry = qy - ny, rz = qz - nz;
        const float dd = sqrtf(rx * rx + ry * ry + rz * rz);
        uint32* pw = (uint32*)&pxs[tid * PXS];
        pw[0] = cvtpk(dd, rx); pw[1] = cvtpk(ry, rz); pw[2] = cvtpk(qx, qy);
        pw[3] = cvtpk(qz, nx); pw[4] = cvtpk(ny, nz);
        #pragma unroll
        for (int z = 5; z < 16; ++z) pw[z] = 0u;
    }
    __syncthreads();

    const f32x4 zf = {0.f, 0.f, 0.f, 0.f};

    // ---- convs via MFMA, partitioned: wave pair per query ----
    {
        bfrag pa1 = *(const bfrag*)&pxs[(qc * 32 + 16 + lrow) * PXS + lgr * 8];
        if (hc == 0) {
            bfrag pa0 = *(const bfrag*)&pxs[(qc * 32 + lrow) * PXS + lgr * 8];
            f32x4 c = __builtin_amdgcn_mfma_f32_16x16x32_bf16(pa0, wcv[0], zf, 0, 0, 0);
            if (lrow < 10) {
                #pragma unroll
                for (int r = 0; r < 4; ++r)
                    fhat[(qc * 32 + lgr * 4 + r) * KS + lrow] =
                        cvt1(fmaxf(c[r] * bnv[0].x + bnv[0].y, 0.f));
            }
            #pragma unroll
            for (int t = 1; t < 3; ++t) {
                f32x4 c2 = __builtin_amdgcn_mfma_f32_16x16x32_bf16(pa1, wcv[t], zf, 0, 0, 0);
                const int o  = (t - 1) * 16 + lrow;       // 0..31
                const int cp = (o < 10) ? o : o + 2;
                #pragma unroll
                for (int r = 0; r < 4; ++r)
                    fhat[(qc * 32 + 16 + lgr * 4 + r) * KS + cp] =
                        cvt1(fmaxf(c2[r] * bnv[t].x + bnv[t].y, 0.f));
            }
        } else {
            #pragma unroll
            for (int t = 0; t < 3; ++t) {
                f32x4 c2 = __builtin_amdgcn_mfma_f32_16x16x32_bf16(pa1, wcv[t], zf, 0, 0, 0);
                const int o = (2 + t) * 16 + lrow;        // 32..79
                if (o < 74) {
                    #pragma unroll
                    for (int r = 0; r < 4; ++r)
                        fhat[(qc * 32 + 16 + lgr * 4 + r) * KS + o + 2] =
                            cvt1(fmaxf(c2[r] * bnv[t].x + bnv[t].y, 0.f));
                }
            }
        }
    }
    __syncthreads();

    // ---- per-query: att GEMM (my nt) + softmax unit(s) ----
    for (int q = 0; q < 4; ++q) {
        bfrag af[2][5];
        #pragma unroll
        for (int mt = 0; mt < 2; ++mt)
            #pragma unroll
            for (int kt = 0; kt < 5; ++kt)
                af[mt][kt] = *(const bfrag*)&fhat[(q * 32 + mt * 16 + lrow) * KS + kt * 32 + lgr * 8];

        f32x4 a0 = zf, a1 = zf;
        #pragma unroll
        for (int kt = 0; kt < 5; ++kt) {
            a0 = __builtin_amdgcn_mfma_f32_16x16x32_bf16(af[0][kt], wb[kt], a0, 0, 0, 0);
            a1 = __builtin_amdgcn_mfma_f32_16x16x32_bf16(af[1][kt], wb[kt], a1, 0, 0, 0);
        }
        softmax32(a0, a1, w, q, lane, lrow, lgr, fhat, aggs);

        if (w >= 4 && (w - 4) == q) {      // extra unit: nt = 8
            f32x4 e0 = zf, e1 = zf;
            #pragma unroll
            for (int kt = 0; kt < 5; ++kt) {
                bfrag b8 = *(const bfrag*)&W1t[((40 + kt) << 9) + (lane << 3)];
                e0 = __builtin_amdgcn_mfma_f32_16x16x32_bf16(af[0][kt], b8, e0, 0, 0, 0);
                e1 = __builtin_amdgcn_mfma_f32_16x16x32_bf16(af[1][kt], b8, e1, 0, 0, 0);
            }
            softmax32(e0, e1, 8, q, lane, lrow, lgr, fhat, aggs);
        }
    }
    // zero-fill aggs cols 10,11 and 146..159 (one wave per query)
    if (w < 4) {
        if (lane < 2)       aggs[w * 160 + 10 + lane] = 0;
        else if (lane < 16) aggs[w * 160 + 144 + lane] = 0;
    }
    // prefetch MLP weights (ot = w) before the barrier
    bfrag wm[5];
    #pragma unroll
    for (int kt = 0; kt < 5; ++kt)
        wm[kt] = *(const bfrag*)&Wm1t[(((w * 5) + kt) << 9) + (lane << 3)];
    __syncthreads();

    // ---- MLP 160->128: wave w owns output tile ot = w ----
    bfrag am[5];
    #pragma unroll
    for (int kt = 0; kt < 5; ++kt)
        am[kt] = *(const bfrag*)&aggs[lrow * 160 + kt * 32 + lgr * 8];
    f32x4 c = zf;
    #pragma unroll
    for (int kt = 0; kt < 5; ++kt)
        c = __builtin_amdgcn_mfma_f32_16x16x32_bf16(am[kt], wm[kt], c, 0, 0, 0);
    if (lgr == 0) {
        const int o = w * 16 + lrow;
        float2 p = *(const float2*)&bn[BN_M1 + o * 2];
        #pragma unroll
        for (int r = 0; r < 4; ++r)
            ft[(size_t)(bq0 + r) * 128 + o] = cvt1(fmaxf(c[r] * p.x + p.y, 0.f));
    }
}

// ---------------- Stage 2: 8 queries/block, 8 waves, nt-partitioned ----------------
__global__ __launch_bounds__(512, 4) void stage2(
    const int* __restrict__ nm_cl, const float* __restrict__ c_q,
    const u16* __restrict__ ws16, float* __restrict__ out)
{
    __shared__ __align__(16) u16 fhat[128 * KS];
    __shared__ __align__(16) u16 pxs[128 * PXS];
    u16* aggs = pxs;

    const int tid  = threadIdx.x;
    const int bq0  = blockIdx.x * 8;
    const int b    = bq0 >> 14;
    const int q0   = bq0 & (Qn - 1);
    const int lane = tid & 63;
    const int w    = tid >> 6;
    const int lrow = lane & 15;
    const int lgr  = lane >> 4;

    const u16* W2t  = ws16 + OFF_W2;
    const u16* Wm2t = ws16 + OFF_WM2;
    const float* bn = (const float*)(ws16 + END_W);
    const u16* ft   = ws16 + OFF_FT;

    // prefetch att weights for my nt = w
    bfrag wb[5];
    #pragma unroll
    for (int kt = 0; kt < 5; ++kt)
        wb[kt] = *(const bfrag*)&W2t[(((w * 5) + kt) << 9) + (lane << 3)];
    // conv cl weight + BN
    bfrag wcl = *(const bfrag*)&ws16[OFF_WCL + (lane << 3)];
    float2 bncl = (lrow < 10) ? *(const float2*)&bn[BN_CL + lrow * 2] : float2{0.f, 0.f};

    for (int u = tid; u < 128 * 15; u += 512) {       // zero cols 10,11 and 140..167
        int row = u / 15, jj = u - row * 15;
        uint32* base = (uint32*)((char*)fhat + row * 336);
        if (jj == 0) base[5] = 0u; else base[69 + jj] = 0u;
    }
    if (tid < 128) {
        const int q = tid >> 4, r = tid & 15;
        const int bq = bq0 + q;
        const int idx = nm_cl[bq * 16 + r];
        const float* nb = c_q + ((size_t)(b << 14) + idx) * 3;
        const float qx = c_q[bq * 3 + 0], qy = c_q[bq * 3 + 1], qz = c_q[bq * 3 + 2];
        const float nx = nb[0], ny = nb[1], nz = nb[2];
        const float rx = qx - nx, ry = qy - ny, rz = qz - nz;
        const float dd = sqrtf(rx * rx + ry * ry + rz * rz);
        uint32* pw = (uint32*)&pxs[tid * PXS];
        pw[0] = cvtpk(dd, rx); pw[1] = cvtpk(ry, rz); pw[2] = cvtpk(qx, qy);
        pw[3] = cvtpk(qz, nx); pw[4] = cvtpk(ny, nz);
        #pragma unroll
        for (int z = 5; z < 16; ++z) pw[z] = 0u;
    }
    // gather f_tilde rows -> fhat cols 12..139 (one row per 64-lane stretch; coalesced)
    for (int u = tid; u < 8192; u += 512) {
        int row = u >> 6, c2 = u & 63;
        int idx = nm_cl[bq0 * 16 + row];
        const uint32* srow = (const uint32*)(ft + (size_t)((b << 14) + idx) * 128);
        *(uint32*)&fhat[row * KS + 12 + c2 * 2] = srow[c2];
    }
    __syncthreads();

    const f32x4 zf = {0.f, 0.f, 0.f, 0.f};

    // ---- conv cl via MFMA: wave w -> query w ----
    {
        bfrag pa = *(const bfrag*)&pxs[(w * 16 + lrow) * PXS + lgr * 8];
        f32x4 c = __builtin_amdgcn_mfma_f32_16x16x32_bf16(pa, wcl, zf, 0, 0, 0);
        if (lrow < 10) {
            #pragma unroll
            for (int r = 0; r < 4; ++r)
                fhat[(w * 16 + lgr * 4 + r) * KS + lrow] =
                    cvt1(fmaxf(c[r] * bncl.x + bncl.y, 0.f));
        }
    }
    __syncthreads();

    // ---- per-query: att GEMM (my nt) + softmax ----
    for (int q = 0; q < 8; ++q) {
        bfrag af[5];
        #pragma unroll
        for (int kt = 0; kt < 5; ++kt)
            af[kt] = *(const bfrag*)&fhat[(q * 16 + lrow) * KS + kt * 32 + lgr * 8];

        f32x4 a0 = zf;
        #pragma unroll
        for (int kt = 0; kt < 5; ++kt)
            a0 = __builtin_amdgcn_mfma_f32_16x16x32_bf16(af[kt], wb[kt], a0, 0, 0, 0);
        softmax16(a0, w, q, lane, lrow, lgr, fhat, aggs);

        if (q == w) {                      // extra unit: nt = 8
            f32x4 e0 = zf;
            #pragma unroll
            for (int kt = 0; kt < 5; ++kt) {
                bfrag b8 = *(const bfrag*)&W2t[((40 + kt) << 9) + (lane << 3)];
                e0 = __builtin_amdgcn_mfma_f32_16x16x32_bf16(af[kt], b8, e0, 0, 0, 0);
            }
            softmax16(e0, 8, q, lane, lrow, lgr, fhat, aggs);
        }
    }
    // zero-fill aggs cols (wave w handles q = w)
    if (lane < 2)       aggs[w * 160 + 10 + lane] = 0;
    else if (lane < 16) aggs[w * 160 + 144 + lane] = 0;
    // prefetch MLP weights (ot = w)
    bfrag wm[5];
    #pragma unroll
    for (int kt = 0; kt < 5; ++kt)
        wm[kt] = *(const bfrag*)&Wm2t[(((w * 5) + kt) << 9) + (lane << 3)];
    __syncthreads();

    // ---- MLP 160->128 -> out (B,128,Q,1) ----
    bfrag am[5];
    #pragma unroll
    for (int kt = 0; kt < 5; ++kt)
        am[kt] = *(const bfrag*)&aggs[lrow * 160 + kt * 32 + lgr * 8];
    f32x4 c = zf;
    #pragma unroll
    for (int kt = 0; kt < 5; ++kt)
        c = __builtin_amdgcn_mfma_f32_16x16x32_bf16(am[kt], wm[kt], c, 0, 0, 0);
    if (lgr < 2) {
        const int o = w * 16 + lrow;
        float2 p = *(const float2*)&bn[BN_M2 + o * 2];
        #pragma unroll
        for (int r = 0; r < 4; ++r) {
            const int qloc = lgr * 4 + r;
            out[((size_t)(b * 128 + o) << 14) + q0 + qloc] = fmaxf(c[r] * p.x + p.y, 0.f);
        }
    }
}

extern "C" void kernel_launch(void* const* d_in, const int* in_sizes, int n_in,
                              void* d_out, int out_size, void* d_ws, size_t ws_size,
                              hipStream_t stream)
{
    const float* feat_lb = (const float*)d_in[0];
    const float* feat_sc = (const float*)d_in[1];
    const int*   nm_lb   = (const int*)d_in[2];
    const int*   nm_sc   = (const int*)d_in[3];
    const float* c_lb    = (const float*)d_in[4];
    const float* c_sc    = (const float*)d_in[5];
    const float* c_q     = (const float*)d_in[6];
    const int*   nm_cl   = (const int*)d_in[7];
    const float* W_lb = (const float*)d_in[8];
    const float* g_lb = (const float*)d_in[9];
    const float* b_lb = (const float*)d_in[10];
    const float* m_lb = (const float*)d_in[11];
    const float* v_lb = (const float*)d_in[12];
    const float* W_sc = (const float*)d_in[13];
    const float* g_sc = (const float*)d_in[14];
    const float* b_sc = (const float*)d_in[15];
    const float* m_sc = (const float*)d_in[16];
    const float* v_sc = (const float*)d_in[17];
    const float* W_fc1  = (const float*)d_in[18];
    const float* W_mlp1 = (const float*)d_in[19];
    const float* g1 = (const float*)d_in[20];
    const float* b1 = (const float*)d_in[21];
    const float* m1 = (const float*)d_in[22];
    const float* v1 = (const float*)d_in[23];
    const float* W_cl = (const float*)d_in[24];
    const float* g_cl = (const float*)d_in[25];
    const float* b_cl = (const float*)d_in[26];
    const float* m_cl = (const float*)d_in[27];
    const float* v_cl = (const float*)d_in[28];
    const float* W_fc2  = (const float*)d_in[29];
    const float* W_mlp2 = (const float*)d_in[30];
    const float* g2 = (const float*)d_in[31];
    const float* b2 = (const float*)d_in[32];
    const float* m2 = (const float*)d_in[33];
    const float* v2 = (const float*)d_in[34];

    u16* ws16 = (u16*)d_ws;
    float* out = (float*)d_out;

    hipLaunchKernelGGL(prep_weights, dim3((PREP_N + 255) / 256), dim3(256), 0, stream,
        W_fc1, W_mlp1, W_fc2, W_mlp2, W_lb, W_sc, W_cl,
        g_lb, b_lb, m_lb, v_lb, g_sc, b_sc, m_sc, v_sc,
        g_cl, b_cl, m_cl, v_cl, g1, b1, m1, v1, g2, b2, m2, v2, ws16);

    hipLaunchKernelGGL(stage1, dim3(2 * Qn / 4), dim3(512), 0, stream,
        feat_lb, feat_sc, nm_lb, nm_sc, c_lb, c_sc, c_q, ws16);

    hipLaunchKernelGGL(stage2, dim3(2 * Qn / 8), dim3(512), 0, stream,
        nm_cl, c_q, ws16, out);
}